// Round 1
// baseline (678.306 us; speedup 1.0000x reference)
//
#include <hip/hip_runtime.h>
#include <hip/hip_bf16.h>

typedef __hip_bfloat16 bf16;
typedef __attribute__((ext_vector_type(8))) short short8;
typedef __attribute__((ext_vector_type(4))) float floatx4;

__device__ __forceinline__ unsigned short f2bf(float x) {
  unsigned u = __builtin_bit_cast(unsigned, x);
  unsigned r = (u + 0x7fffu + ((u >> 16) & 1u)) >> 16;
  return (unsigned short)r;
}

#define GLL(g, l) __builtin_amdgcn_global_load_lds(                                  \
    (const __attribute__((address_space(1))) void*)(g),                              \
    (__attribute__((address_space(3))) void*)(l), 16, 0, 0)

// ---------------- weight transpose+convert: fp32 [K][N] -> bf16 [N][K] ----------
__global__ __launch_bounds__(256) void wtrans_kernel(const float* __restrict__ in,
                                                     bf16* __restrict__ out,
                                                     int K, int N) {
  __shared__ float tile[32][33];
  int tx = threadIdx.x, ty = threadIdx.y;
  int n0 = blockIdx.x * 32, k0 = blockIdx.y * 32;
#pragma unroll
  for (int i = 0; i < 32; i += 8)
    tile[ty + i][tx] = in[(size_t)(k0 + ty + i) * N + (n0 + tx)];
  __syncthreads();
#pragma unroll
  for (int i = 0; i < 32; i += 8)
    out[(size_t)(n0 + ty + i) * K + (k0 + tx)] = __float2bfloat16(tile[tx][ty + i]);
}

// ---------------- bf16 transpose, batched: in [R][C] -> out [C][R] --------------
__global__ __launch_bounds__(256) void btrans_kernel(const bf16* __restrict__ in,
                                                     bf16* __restrict__ out,
                                                     int R, int C) {
  __shared__ bf16 tile[32][33];
  size_t boff = (size_t)blockIdx.z * R * C;
  int tx = threadIdx.x, ty = threadIdx.y;
  int c0 = blockIdx.x * 32, r0 = blockIdx.y * 32;
#pragma unroll
  for (int i = 0; i < 32; i += 8)
    tile[ty + i][tx] = in[boff + (size_t)(r0 + ty + i) * C + (c0 + tx)];
  __syncthreads();
#pragma unroll
  for (int i = 0; i < 32; i += 8)
    out[boff + (size_t)(c0 + ty + i) * R + (r0 + tx)] = tile[tx][ty + i];
}

// ---------------- LayerNorm fp32 -> bf16, D=1024, one block(256)/row ------------
__global__ __launch_bounds__(256) void ln_kernel(const float* __restrict__ x,
                                                 const float* __restrict__ g,
                                                 const float* __restrict__ b,
                                                 bf16* __restrict__ out) {
  const int D = 1024;
  size_t row = blockIdx.x;
  int t = threadIdx.x;
  float4 v = ((const float4*)(x + row * D))[t];
  float s  = v.x + v.y + v.z + v.w;
  float ss = v.x * v.x + v.y * v.y + v.z * v.z + v.w * v.w;
#pragma unroll
  for (int off = 32; off > 0; off >>= 1) {
    s  += __shfl_xor(s, off);
    ss += __shfl_xor(ss, off);
  }
  __shared__ float rs[4], rss[4];
  int wv = t >> 6;
  if ((t & 63) == 0) { rs[wv] = s; rss[wv] = ss; }
  __syncthreads();
  s  = rs[0] + rs[1] + rs[2] + rs[3];
  ss = rss[0] + rss[1] + rss[2] + rss[3];
  float mu  = s * (1.f / D);
  float inv = rsqrtf(ss * (1.f / D) - mu * mu + 1e-5f);
  float4 gv = ((const float4*)g)[t];
  float4 bv = ((const float4*)b)[t];
  ushort4 o;
  o.x = f2bf((v.x - mu) * inv * gv.x + bv.x);
  o.y = f2bf((v.y - mu) * inv * gv.y + bv.y);
  o.z = f2bf((v.z - mu) * inv * gv.z + bv.z);
  o.w = f2bf((v.w - mu) * inv * gv.w + bv.w);
  ((ushort4*)(out + row * D))[t] = o;
}

// ---------------- softmax: fp32 row (2048) -> bf16 written in place -------------
__global__ __launch_bounds__(256) void softmax_kernel(float* sc) {
  const int S = 2048;
  float* p = sc + (size_t)blockIdx.x * S;
  int t = threadIdx.x;
  float4 v0 = ((const float4*)p)[2 * t];
  float4 v1 = ((const float4*)p)[2 * t + 1];
  float f[8] = {v0.x, v0.y, v0.z, v0.w, v1.x, v1.y, v1.z, v1.w};
  float m = f[0];
#pragma unroll
  for (int j = 1; j < 8; ++j) m = fmaxf(m, f[j]);
#pragma unroll
  for (int off = 32; off > 0; off >>= 1) m = fmaxf(m, __shfl_xor(m, off));
  __shared__ float r1[4], r2[4];
  int wv = t >> 6;
  if ((t & 63) == 0) r1[wv] = m;
  __syncthreads();
  m = fmaxf(fmaxf(r1[0], r1[1]), fmaxf(r1[2], r1[3]));
  float s = 0.f;
#pragma unroll
  for (int j = 0; j < 8; ++j) { f[j] = __expf(f[j] - m); s += f[j]; }
#pragma unroll
  for (int off = 32; off > 0; off >>= 1) s += __shfl_xor(s, off);
  if ((t & 63) == 0) r2[wv] = s;
  __syncthreads();
  s = r2[0] + r2[1] + r2[2] + r2[3];
  float inv = 1.f / s;
  unsigned u0 = f2bf(f[0] * inv), u1 = f2bf(f[1] * inv);
  unsigned u2 = f2bf(f[2] * inv), u3 = f2bf(f[3] * inv);
  unsigned u4 = f2bf(f[4] * inv), u5 = f2bf(f[5] * inv);
  unsigned u6 = f2bf(f[6] * inv), u7 = f2bf(f[7] * inv);
  uint4 o;
  o.x = u0 | (u1 << 16);
  o.y = u2 | (u3 << 16);
  o.z = u4 | (u5 << 16);
  o.w = u6 | (u7 << 16);
  ((uint4*)p)[t] = o;  // bf16 row occupies first half of the fp32 row
}

// ---------------- GEMM: C[M,N] = alpha*(A[M,K] @ BT[N,K]^T) (+bias)(+gelu)(+res) -
// m97 structure: 128x128 tile, 4 waves, 16x16x32 bf16 MFMA, BK=32,
// double-buffered LDS via global_load_lds width 16.
template <bool OUT_BF16, bool HAS_BIAS, bool HAS_RES, bool GELU>
__global__ __launch_bounds__(256) void gemm_bt(const bf16* __restrict__ A, int lda,
                                               const bf16* __restrict__ BT,
                                               void* Cv,
                                               const float* __restrict__ bias,
                                               const float* res,
                                               int M, int N, int K, float alpha) {
  __shared__ bf16 As[2][128 * 32];
  __shared__ bf16 Bs[2][128 * 32];
  const int tid = threadIdx.x;
  const int wave = tid >> 6, lane = tid & 63;
  const int lr = lane & 15, lq = lane >> 4;
  const int wm = wave >> 1, wn = wave & 1;
  const int m0 = blockIdx.y * 128, n0 = blockIdx.x * 128;

  const int srow = tid >> 2;         // 0..63
  const int scol = (tid & 3) * 8;    // 0,8,16,24
  const bf16* ga = A + (size_t)(m0 + srow) * lda + scol;
  const bf16* gb = BT + (size_t)(n0 + srow) * K + scol;
  bf16* lab = &As[0][0] + (wave * 16) * 32;  // wave-uniform LDS base
  bf16* lbb = &Bs[0][0] + (wave * 16) * 32;

  floatx4 acc[4][4] = {};

  const int nk = K >> 5;
  // prologue: stage k-tile 0 into buffer 0
  GLL(ga, lab);
  GLL(ga + (size_t)64 * lda, lab + 64 * 32);
  GLL(gb, lbb);
  GLL(gb + (size_t)64 * K, lbb + 64 * 32);
  __syncthreads();

  int cur = 0;
  for (int kt = 0; kt < nk; ++kt) {
    if (kt + 1 < nk) {  // prefetch next k-tile into the other buffer
      const bf16* a1 = ga + (kt + 1) * 32;
      const bf16* b1 = gb + (kt + 1) * 32;
      bf16* la = lab + (cur ^ 1) * (128 * 32);
      bf16* lb = lbb + (cur ^ 1) * (128 * 32);
      GLL(a1, la);
      GLL(a1 + (size_t)64 * lda, la + 64 * 32);
      GLL(b1, lb);
      GLL(b1 + (size_t)64 * K, lb + 64 * 32);
    }
    const bf16* Ab = &As[cur][0];
    const bf16* Bb = &Bs[cur][0];
    short8 af[4], bfv[4];
    const int aoff = (wm * 64 + lr) * 32 + lq * 8;
    const int boff = (wn * 64 + lr) * 32 + lq * 8;
#pragma unroll
    for (int i = 0; i < 4; ++i) af[i] = *(const short8*)(Ab + aoff + i * 16 * 32);
#pragma unroll
    for (int j = 0; j < 4; ++j) bfv[j] = *(const short8*)(Bb + boff + j * 16 * 32);
#pragma unroll
    for (int i = 0; i < 4; ++i)
#pragma unroll
      for (int j = 0; j < 4; ++j)
        acc[i][j] = __builtin_amdgcn_mfma_f32_16x16x32_bf16(af[i], bfv[j], acc[i][j], 0, 0, 0);
    __syncthreads();
    cur ^= 1;
  }

  // epilogue: D-frag mapping col=lane&15, row=(lane>>4)*4+r  [m89-verified]
  float* Cf = (float*)Cv;
  bf16* Cb = (bf16*)Cv;
#pragma unroll
  for (int i = 0; i < 4; ++i) {
    const int row = m0 + wm * 64 + i * 16 + lq * 4;
#pragma unroll
    for (int j = 0; j < 4; ++j) {
      const int col = n0 + wn * 64 + j * 16 + lr;
      float bb = HAS_BIAS ? bias[col] : 0.f;
#pragma unroll
      for (int r = 0; r < 4; ++r) {
        float val = acc[i][j][r] * alpha + bb;
        if (GELU) val = 0.5f * val * (1.f + erff(val * 0.70710678118654752f));
        if (HAS_RES) val += res[(size_t)(row + r) * N + col];
        size_t idx = (size_t)(row + r) * N + col;
        if (OUT_BF16) Cb[idx] = __float2bfloat16(val);
        else Cf[idx] = val;
      }
    }
  }
}

extern "C" void kernel_launch(void* const* d_in, const int* in_sizes, int n_in,
                              void* d_out, int out_size, void* d_ws, size_t ws_size,
                              hipStream_t stream) {
  const int B = 4, S = 2048, D = 1024, DFF = 4096;
  const int M = B * S;
  const float* x   = (const float*)d_in[0];
  const float* wq  = (const float*)d_in[1];
  const float* bq  = (const float*)d_in[2];
  const float* wk  = (const float*)d_in[3];
  const float* bk  = (const float*)d_in[4];
  const float* wv  = (const float*)d_in[5];
  const float* bv  = (const float*)d_in[6];
  const float* wo  = (const float*)d_in[7];
  const float* bo  = (const float*)d_in[8];
  const float* w1  = (const float*)d_in[9];
  const float* b1  = (const float*)d_in[10];
  const float* w2  = (const float*)d_in[11];
  const float* b2  = (const float*)d_in[12];
  const float* g1  = (const float*)d_in[13];
  const float* be1 = (const float*)d_in[14];
  const float* g2  = (const float*)d_in[15];
  const float* be2 = (const float*)d_in[16];
  float* out = (float*)d_out;

  // workspace arena (peak 120 MB):
  //   [0,2)wqT [2,4)wkT [4,6)wvT [6,8)woT [8,16)w1T [16,24)w2T
  //   [24,40) h: h1 -> ctx -> h2     [40,104) q,k,v,vT  (later: mlp hidden 64MB)
  //   [104,120) scores fp32 (per batch; softmaxed bf16 written in place)
  char* wsb = (char*)d_ws;
  const size_t MB1 = 1ull << 20;
  bf16* wqT = (bf16*)(wsb + 0 * MB1);
  bf16* wkT = (bf16*)(wsb + 2 * MB1);
  bf16* wvT = (bf16*)(wsb + 4 * MB1);
  bf16* woT = (bf16*)(wsb + 6 * MB1);
  bf16* w1T = (bf16*)(wsb + 8 * MB1);
  bf16* w2T = (bf16*)(wsb + 16 * MB1);
  bf16* h   = (bf16*)(wsb + 24 * MB1);
  bf16* q   = (bf16*)(wsb + 40 * MB1);
  bf16* kk  = (bf16*)(wsb + 56 * MB1);
  bf16* v   = (bf16*)(wsb + 72 * MB1);
  bf16* vT  = (bf16*)(wsb + 88 * MB1);
  float* sc = (float*)(wsb + 104 * MB1);
  bf16* hidden = (bf16*)(wsb + 40 * MB1);

  dim3 tb(32, 8);
  // weights -> bf16 transposed [N][K]
  wtrans_kernel<<<dim3(D / 32, D / 32), tb, 0, stream>>>(wq, wqT, D, D);
  wtrans_kernel<<<dim3(D / 32, D / 32), tb, 0, stream>>>(wk, wkT, D, D);
  wtrans_kernel<<<dim3(D / 32, D / 32), tb, 0, stream>>>(wv, wvT, D, D);
  wtrans_kernel<<<dim3(D / 32, D / 32), tb, 0, stream>>>(wo, woT, D, D);
  wtrans_kernel<<<dim3(DFF / 32, D / 32), tb, 0, stream>>>(w1, w1T, D, DFF);
  wtrans_kernel<<<dim3(D / 32, DFF / 32), tb, 0, stream>>>(w2, w2T, DFF, D);

  // h1 = LN1(x)
  ln_kernel<<<M, 256, 0, stream>>>(x, g1, be1, h);

  // q,k,v = h1 @ w{q,k,v} + b
  gemm_bt<true, true, false, false><<<dim3(D / 128, M / 128), 256, 0, stream>>>(
      h, D, wqT, q, bq, nullptr, M, D, D, 1.f);
  gemm_bt<true, true, false, false><<<dim3(D / 128, M / 128), 256, 0, stream>>>(
      h, D, wkT, kk, bk, nullptr, M, D, D, 1.f);
  gemm_bt<true, true, false, false><<<dim3(D / 128, M / 128), 256, 0, stream>>>(
      h, D, wvT, v, bv, nullptr, M, D, D, 1.f);

  // vT[b] = v[b]^T
  btrans_kernel<<<dim3(D / 32, S / 32, B), tb, 0, stream>>>(v, vT, S, D);

  // attention, per batch through one fp32 score buffer
  for (int b = 0; b < B; ++b) {
    gemm_bt<false, false, false, false><<<dim3(S / 128, S / 128), 256, 0, stream>>>(
        q + (size_t)b * S * D, D, kk + (size_t)b * S * D, sc, nullptr, nullptr,
        S, S, D, 0.125f);
    softmax_kernel<<<S, 256, 0, stream>>>(sc);
    // attn (bf16, row pitch 2*S elems, in-place over fp32 rows) @ vT^T -> ctx
    gemm_bt<true, false, false, false><<<dim3(D / 128, S / 128), 256, 0, stream>>>(
        (const bf16*)sc, 2 * S, vT + (size_t)b * D * S, h + (size_t)b * S * D,
        nullptr, nullptr, S, D, S, 1.f);
  }

  // x2 = ctx @ wo + bo + x   -> d_out (fp32)
  gemm_bt<false, true, true, false><<<dim3(D / 128, M / 128), 256, 0, stream>>>(
      h, D, woT, out, bo, x, M, D, D, 1.f);

  // h2 = LN2(x2)
  ln_kernel<<<M, 256, 0, stream>>>(out, g2, be2, h);

  // hidden = gelu(h2 @ w1 + b1)
  gemm_bt<true, true, false, true><<<dim3(DFF / 128, M / 128), 256, 0, stream>>>(
      h, D, w1T, hidden, b1, nullptr, M, DFF, D, 1.f);

  // out = hidden @ w2 + b2 + x2   (in-place residual from d_out)
  gemm_bt<false, true, true, false><<<dim3(D / 128, M / 128), 256, 0, stream>>>(
      hidden, DFF, w2T, out, b2, out, M, D, DFF, 1.f);
}

// Round 2
// 536.224 us; speedup vs baseline: 1.2650x; 1.2650x over previous
//
#include <hip/hip_runtime.h>
#include <hip/hip_bf16.h>

typedef __hip_bfloat16 bf16;
typedef __attribute__((ext_vector_type(8))) short short8;
typedef __attribute__((ext_vector_type(4))) float floatx4;

__device__ __forceinline__ unsigned short f2bf(float x) {
  unsigned u = __builtin_bit_cast(unsigned, x);
  unsigned r = (u + 0x7fffu + ((u >> 16) & 1u)) >> 16;
  return (unsigned short)r;
}

#define GLL(g, l) __builtin_amdgcn_global_load_lds(                                  \
    (const __attribute__((address_space(1))) void*)(g),                              \
    (__attribute__((address_space(3))) void*)(l), 16, 0, 0)

template <int N> __device__ __forceinline__ void vmwait() {
  if constexpr (N == 8) asm volatile("s_waitcnt vmcnt(8)" ::: "memory");
  else if constexpr (N == 6) asm volatile("s_waitcnt vmcnt(6)" ::: "memory");
  else if constexpr (N == 4) asm volatile("s_waitcnt vmcnt(4)" ::: "memory");
  else if constexpr (N == 3) asm volatile("s_waitcnt vmcnt(3)" ::: "memory");
  else asm volatile("s_waitcnt vmcnt(0)" ::: "memory");
}

// ---------------- weight transpose+convert: fp32 [K][N] -> bf16 [N][K] ----------
__global__ __launch_bounds__(256) void wtrans_kernel(const float* __restrict__ in,
                                                     bf16* __restrict__ out,
                                                     int K, int N) {
  __shared__ float tile[32][33];
  int tx = threadIdx.x, ty = threadIdx.y;
  int n0 = blockIdx.x * 32, k0 = blockIdx.y * 32;
#pragma unroll
  for (int i = 0; i < 32; i += 8)
    tile[ty + i][tx] = in[(size_t)(k0 + ty + i) * N + (n0 + tx)];
  __syncthreads();
#pragma unroll
  for (int i = 0; i < 32; i += 8)
    out[(size_t)(n0 + ty + i) * K + (k0 + tx)] = __float2bfloat16(tile[tx][ty + i]);
}

// ---------------- bf16 transpose, batched, with pitches -------------------------
__global__ __launch_bounds__(256) void btrans_kernel(const bf16* __restrict__ in,
                                                     int ldin, size_t sIn,
                                                     bf16* __restrict__ out,
                                                     int ldout, size_t sOut) {
  __shared__ bf16 tile[32][33];
  int tx = threadIdx.x, ty = threadIdx.y;
  int c0 = blockIdx.x * 32, r0 = blockIdx.y * 32;
  size_t bi = sIn * blockIdx.z, bo = sOut * blockIdx.z;
#pragma unroll
  for (int i = 0; i < 32; i += 8)
    tile[ty + i][tx] = in[bi + (size_t)(r0 + ty + i) * ldin + (c0 + tx)];
  __syncthreads();
#pragma unroll
  for (int i = 0; i < 32; i += 8)
    out[bo + (size_t)(c0 + ty + i) * ldout + (r0 + tx)] = tile[tx][ty + i];
}

// ---------------- LayerNorm fp32 -> bf16, D=1024, one block(256)/row ------------
__global__ __launch_bounds__(256) void ln_kernel(const float* __restrict__ x,
                                                 const float* __restrict__ g,
                                                 const float* __restrict__ b,
                                                 bf16* __restrict__ out) {
  const int D = 1024;
  size_t row = blockIdx.x;
  int t = threadIdx.x;
  float4 v = ((const float4*)(x + row * D))[t];
  float s  = v.x + v.y + v.z + v.w;
  float ss = v.x * v.x + v.y * v.y + v.z * v.z + v.w * v.w;
#pragma unroll
  for (int off = 32; off > 0; off >>= 1) {
    s  += __shfl_xor(s, off);
    ss += __shfl_xor(ss, off);
  }
  __shared__ float rs[4], rss[4];
  int wv = t >> 6;
  if ((t & 63) == 0) { rs[wv] = s; rss[wv] = ss; }
  __syncthreads();
  s  = rs[0] + rs[1] + rs[2] + rs[3];
  ss = rss[0] + rss[1] + rss[2] + rss[3];
  float mu  = s * (1.f / D);
  float inv = rsqrtf(ss * (1.f / D) - mu * mu + 1e-5f);
  float4 gv = ((const float4*)g)[t];
  float4 bv = ((const float4*)b)[t];
  ushort4 o;
  o.x = f2bf((v.x - mu) * inv * gv.x + bv.x);
  o.y = f2bf((v.y - mu) * inv * gv.y + bv.y);
  o.z = f2bf((v.z - mu) * inv * gv.z + bv.z);
  o.w = f2bf((v.w - mu) * inv * gv.w + bv.w);
  ((ushort4*)(out + row * D))[t] = o;
}

// ---------------- softmax: fp32 row (2048) -> bf16 written in place -------------
__global__ __launch_bounds__(256) void softmax_kernel(float* sc) {
  const int S = 2048;
  float* p = sc + (size_t)blockIdx.x * S;
  int t = threadIdx.x;
  float4 v0 = ((const float4*)p)[2 * t];
  float4 v1 = ((const float4*)p)[2 * t + 1];
  float f[8] = {v0.x, v0.y, v0.z, v0.w, v1.x, v1.y, v1.z, v1.w};
  float m = f[0];
#pragma unroll
  for (int j = 1; j < 8; ++j) m = fmaxf(m, f[j]);
#pragma unroll
  for (int off = 32; off > 0; off >>= 1) m = fmaxf(m, __shfl_xor(m, off));
  __shared__ float r1[4], r2[4];
  int wv = t >> 6;
  if ((t & 63) == 0) r1[wv] = m;
  __syncthreads();
  m = fmaxf(fmaxf(r1[0], r1[1]), fmaxf(r1[2], r1[3]));
  float s = 0.f;
#pragma unroll
  for (int j = 0; j < 8; ++j) { f[j] = __expf(f[j] - m); s += f[j]; }
#pragma unroll
  for (int off = 32; off > 0; off >>= 1) s += __shfl_xor(s, off);
  if ((t & 63) == 0) r2[wv] = s;
  __syncthreads();
  s = r2[0] + r2[1] + r2[2] + r2[3];
  float inv = 1.f / s;
  unsigned u0 = f2bf(f[0] * inv), u1 = f2bf(f[1] * inv);
  unsigned u2 = f2bf(f[2] * inv), u3 = f2bf(f[3] * inv);
  unsigned u4 = f2bf(f[4] * inv), u5 = f2bf(f[5] * inv);
  unsigned u6 = f2bf(f[6] * inv), u7 = f2bf(f[7] * inv);
  uint4 o;
  o.x = u0 | (u1 << 16);
  o.y = u2 | (u3 << 16);
  o.z = u4 | (u5 << 16);
  o.w = u6 | (u7 << 16);
  ((uint4*)p)[t] = o;
}

// ---------------- phased GEMM: C = alpha*(A[M,K] @ BT[N,K]^T) (+bias)(+gelu)(+res)
// 256 x (NF*64) tile, BK=32, 8 waves (2Mx4N, per-wave 128 x NF*16), 4-deep
// circular LDS buffers staged via global_load_lds w16, counted vmcnt (T4),
// XOR-swizzled LDS (T2, inverse swizzle pre-applied to global src per rule #21),
// setprio around MFMA clusters (T5), bijective XCD block swizzle (T1).
template <int NF, bool OUT_BF16, bool HAS_BIAS, bool HAS_RES, bool GELU>
__global__ __launch_bounds__(512, 2) void gemm256(
    const bf16* __restrict__ A, int lda, size_t sA,
    const bf16* __restrict__ BT, int ldb, size_t sB,
    void* Cv, size_t sC,
    const float* __restrict__ bias, const float* res,
    int N, int K, float alpha, int gx, int gy) {
  constexpr int BN = NF * 64;
  constexpr int LOADS = 2 + NF / 2;  // gload_lds issues per K-tile per thread
  __shared__ bf16 As[4][256 * 32];
  __shared__ bf16 Bs[4][BN * 32];

  const int tid = threadIdx.x;
  const int lane = tid & 63;
  const int wave = tid >> 6;
  const int wm = wave >> 2, wn = wave & 3;
  const int lr = lane & 15, lq = lane >> 4;
  const int cA = (lq ^ ((lr >> 1) & 3)) * 8;  // swizzled k-chunk (elem offset)

  int id = blockIdx.x;
  const int nwg = gridDim.x;
  if ((nwg & 7) == 0) id = (id & 7) * (nwg >> 3) + (id >> 3);  // XCD swizzle
  const int bx = id % gx;
  const int rem = id / gx;
  const int by = rem % gy;
  const int bz = rem / gy;
  const int m0 = by * 256, n0 = bx * BN;

  const int srow = tid >> 2;                           // staging row 0..127
  const int kcol = ((tid & 3) ^ ((tid >> 3) & 3)) * 8; // inverse-swizzled src chunk

  const bf16* ga = A + sA * bz + (size_t)(m0 + srow) * lda + kcol;
  const bf16* gb = BT + sB * bz + (size_t)(n0 + srow) * ldb + kcol;

  floatx4 acc[8][NF] = {};
  const int nk = K >> 5;

  auto stageA = [&](int u) {
    const bf16* s = ga + (size_t)u * 32;
    bf16* d = &As[u & 3][0] + tid * 8;
    GLL(s, d);
    GLL(s + (size_t)128 * lda, d + 4096);
  };
  auto stageB = [&](int u) {
    const bf16* s = gb + (size_t)u * 32;
    bf16* d = &Bs[u & 3][0] + tid * 8;
    GLL(s, d);
    if constexpr (NF == 4) GLL(s + (size_t)128 * ldb, d + 4096);
  };

  // prologue: stage tiles 0..2 into bufs 0..2 (nk >= 32 in all uses)
  stageA(0); stageB(0);
  stageA(1); stageB(1);
  stageA(2); stageB(2);

  const int arow = wm * 128 + lr;
  const int brow = wn * (NF * 16) + lr;

  for (int t = 0; t < nk; ++t) {
    // counted wait: my tile-t loads retired; tiles t+1,t+2 stay in flight
    if (t + 2 < nk) vmwait<2 * LOADS>();
    else if (t + 1 < nk) vmwait<LOADS>();
    else vmwait<0>();
    __builtin_amdgcn_sched_barrier(0);
    __builtin_amdgcn_s_barrier();  // all waves' tile-t data now in LDS

    const bf16* Ab = &As[t & 3][0];
    const bf16* Bb = &Bs[t & 3][0];

    // ---- phase A: stage-issue (A half of t+3) || ds_read || MFMA rows 0-63
    if (t + 3 < nk) stageA(t + 3);
    short8 bfrag[NF], af[4];
#pragma unroll
    for (int ni = 0; ni < NF; ++ni)
      bfrag[ni] = *(const short8*)(Bb + (brow + ni * 16) * 32 + cA);
#pragma unroll
    for (int mi = 0; mi < 4; ++mi)
      af[mi] = *(const short8*)(Ab + (arow + mi * 16) * 32 + cA);
    __builtin_amdgcn_s_setprio(1);
#pragma unroll
    for (int mi = 0; mi < 4; ++mi)
#pragma unroll
      for (int ni = 0; ni < NF; ++ni)
        acc[mi][ni] =
            __builtin_amdgcn_mfma_f32_16x16x32_bf16(af[mi], bfrag[ni], acc[mi][ni], 0, 0, 0);
    __builtin_amdgcn_s_setprio(0);
    __builtin_amdgcn_s_barrier();

    // ---- phase B: stage-issue (B half of t+3) || ds_read || MFMA rows 64-127
    if (t + 3 < nk) stageB(t + 3);
    short8 af2[4];
#pragma unroll
    for (int mi = 0; mi < 4; ++mi)
      af2[mi] = *(const short8*)(Ab + (arow + (4 + mi) * 16) * 32 + cA);
    __builtin_amdgcn_s_setprio(1);
#pragma unroll
    for (int mi = 0; mi < 4; ++mi)
#pragma unroll
      for (int ni = 0; ni < NF; ++ni)
        acc[4 + mi][ni] =
            __builtin_amdgcn_mfma_f32_16x16x32_bf16(af2[mi], bfrag[ni], acc[4 + mi][ni], 0, 0, 0);
    __builtin_amdgcn_s_setprio(0);
    // my LDS reads have landed before next barrier -> next-tile staging can't stomp
    asm volatile("s_waitcnt lgkmcnt(0)" ::: "memory");
    __builtin_amdgcn_sched_barrier(0);
  }

  // epilogue: C/D frag map col=lane&15, row=(lane>>4)*4+r [m89-verified]
  float* Cf = (float*)Cv;
  bf16* Cb = (bf16*)Cv;
  const size_t cb = sC * bz;
#pragma unroll
  for (int mi = 0; mi < 8; ++mi) {
    const int row = m0 + wm * 128 + mi * 16 + lq * 4;
#pragma unroll
    for (int ni = 0; ni < NF; ++ni) {
      const int col = n0 + wn * (NF * 16) + ni * 16 + lr;
      const float bb = HAS_BIAS ? bias[col] : 0.f;
#pragma unroll
      for (int r = 0; r < 4; ++r) {
        float val = acc[mi][ni][r] * alpha + bb;
        if (GELU) val = 0.5f * val * (1.f + erff(val * 0.70710678118654752f));
        if (HAS_RES) val += res[(size_t)(row + r) * N + col];
        const size_t idx = cb + (size_t)(row + r) * N + col;
        if (OUT_BF16) Cb[idx] = __float2bfloat16(val);
        else Cf[idx] = val;
      }
    }
  }
}

extern "C" void kernel_launch(void* const* d_in, const int* in_sizes, int n_in,
                              void* d_out, int out_size, void* d_ws, size_t ws_size,
                              hipStream_t stream) {
  const int B = 4, S = 2048, D = 1024, DFF = 4096;
  const int M = B * S;
  const float* x   = (const float*)d_in[0];
  const float* wq  = (const float*)d_in[1];
  const float* bq  = (const float*)d_in[2];
  const float* wk  = (const float*)d_in[3];
  const float* bk  = (const float*)d_in[4];
  const float* wv  = (const float*)d_in[5];
  const float* bv  = (const float*)d_in[6];
  const float* wo  = (const float*)d_in[7];
  const float* bo  = (const float*)d_in[8];
  const float* w1  = (const float*)d_in[9];
  const float* b1  = (const float*)d_in[10];
  const float* w2  = (const float*)d_in[11];
  const float* b2  = (const float*)d_in[12];
  const float* g1  = (const float*)d_in[13];
  const float* be1 = (const float*)d_in[14];
  const float* g2  = (const float*)d_in[15];
  const float* be2 = (const float*)d_in[16];
  float* out = (float*)d_out;

  // workspace arena:
  //  0-6   wqkvT [3072][1024] bf16      6-8   woT        8-16 w1T   16-24 w2T
  //  24    bqkv (12KB)                  25-41 h (bf16 MxD)
  //  41-89 qkv (bf16 Mx3072)  / later hidden (bf16 MxDFF, 41-105)
  //  89+   per-chunk: vT (4c MB) then scores fp32 (16c MB)  [c adaptive]
  char* wsb = (char*)d_ws;
  const size_t MB1 = 1ull << 20;
  bf16* wqkvT = (bf16*)(wsb + 0 * MB1);
  bf16* woT   = (bf16*)(wsb + 6 * MB1);
  bf16* w1T   = (bf16*)(wsb + 8 * MB1);
  bf16* w2T   = (bf16*)(wsb + 16 * MB1);
  float* bqkv = (float*)(wsb + 24 * MB1);
  bf16* h     = (bf16*)(wsb + 25 * MB1);
  bf16* qkv   = (bf16*)(wsb + 41 * MB1);
  bf16* hidden = (bf16*)(wsb + 41 * MB1);
  char* attn  = wsb + 89 * MB1;

  int chunk = 1;
  if (ws_size > 89 * MB1) {
    size_t c = (ws_size - 89 * MB1) / (20 * MB1);
    chunk = (int)(c > 4 ? 4 : (c < 1 ? 1 : c));
  }
  bf16* vTc = (bf16*)attn;                              // [c][D][S]
  float* sc = (float*)(attn + (size_t)chunk * 4 * MB1); // [c][S][S] fp32

  dim3 tb(32, 8);
  // weights -> bf16 [N][K]; q,k,v stacked into wqkvT rows 0/1024/2048
  wtrans_kernel<<<dim3(32, 32), tb, 0, stream>>>(wq, wqkvT, D, D);
  wtrans_kernel<<<dim3(32, 32), tb, 0, stream>>>(wk, wqkvT + (size_t)1024 * 1024, D, D);
  wtrans_kernel<<<dim3(32, 32), tb, 0, stream>>>(wv, wqkvT + (size_t)2048 * 1024, D, D);
  wtrans_kernel<<<dim3(32, 32), tb, 0, stream>>>(wo, woT, D, D);
  wtrans_kernel<<<dim3(128, 32), tb, 0, stream>>>(w1, w1T, D, DFF);
  wtrans_kernel<<<dim3(32, 128), tb, 0, stream>>>(w2, w2T, DFF, D);
  hipMemcpyAsync(bqkv, bq, 4096, hipMemcpyDeviceToDevice, stream);
  hipMemcpyAsync(bqkv + 1024, bk, 4096, hipMemcpyDeviceToDevice, stream);
  hipMemcpyAsync(bqkv + 2048, bv, 4096, hipMemcpyDeviceToDevice, stream);

  // h = LN1(x)
  ln_kernel<<<M, 256, 0, stream>>>(x, g1, be1, h);

  // qkv = h @ [wq|wk|wv] + [bq|bk|bv]   (N=3072, BN=128 -> 768 blocks)
  gemm256<2, true, true, false, false><<<24 * 32, 512, 0, stream>>>(
      h, D, 0, wqkvT, D, 0, qkv, 0, bqkv, nullptr, 3072, D, 1.f, 24, 32);

  // attention in chunks of `chunk` batches
  for (int b0 = 0; b0 < B; b0 += chunk) {
    int c = (B - b0 < chunk) ? (B - b0) : chunk;
    // vT[z] = v[z]^T  (v = qkv cols 2048..3071)
    btrans_kernel<<<dim3(32, 64, c), tb, 0, stream>>>(
        qkv + (size_t)b0 * S * 3072 + 2048, 3072, (size_t)S * 3072,
        vTc, S, (size_t)D * S);
    // scores = q @ k^T * 0.125  (fp32)
    gemm256<4, false, false, false, false><<<64 * c, 512, 0, stream>>>(
        qkv + (size_t)b0 * S * 3072, 3072, (size_t)S * 3072,
        qkv + (size_t)b0 * S * 3072 + 1024, 3072, (size_t)S * 3072,
        sc, (size_t)S * S, nullptr, nullptr, S, D, 0.125f, 8, 8);
    softmax_kernel<<<c * S, 256, 0, stream>>>(sc);
    // ctx = probs @ vT^T  (probs bf16 in-place over fp32 rows, pitch 2S)
    gemm256<2, true, false, false, false><<<64 * c, 512, 0, stream>>>(
        (const bf16*)sc, 2 * S, (size_t)S * 2 * S,
        vTc, S, (size_t)D * S,
        h + (size_t)b0 * S * D, (size_t)S * D, nullptr, nullptr, D, S, 1.f, 8, 8);
  }

  // x2 = ctx @ wo + bo + x  -> d_out (fp32)
  gemm256<2, false, true, true, false><<<8 * 32, 512, 0, stream>>>(
      h, D, 0, woT, D, 0, out, 0, bo, x, D, D, 1.f, 8, 32);

  // h = LN2(x2)
  ln_kernel<<<M, 256, 0, stream>>>(out, g2, be2, h);

  // hidden = gelu(h @ w1 + b1)
  gemm256<4, true, true, false, true><<<16 * 32, 512, 0, stream>>>(
      h, D, 0, w1T, D, 0, hidden, 0, b1, nullptr, DFF, D, 1.f, 16, 32);

  // out = hidden @ w2 + b2 + x2  (in-place residual)
  gemm256<2, false, true, true, false><<<8 * 32, 512, 0, stream>>>(
      hidden, DFF, 0, w2T, DFF, 0, out, 0, b2, out, D, DFF, 1.f, 8, 32);
}

// Round 3
// 492.020 us; speedup vs baseline: 1.3786x; 1.0898x over previous
//
#include <hip/hip_runtime.h>
#include <hip/hip_bf16.h>

typedef __hip_bfloat16 bf16;
typedef __attribute__((ext_vector_type(8))) short short8;
typedef __attribute__((ext_vector_type(4))) float floatx4;

__device__ __forceinline__ unsigned short f2bf(float x) {
  unsigned u = __builtin_bit_cast(unsigned, x);
  unsigned r = (u + 0x7fffu + ((u >> 16) & 1u)) >> 16;
  return (unsigned short)r;
}

#define GLL(g, l) __builtin_amdgcn_global_load_lds(                                  \
    (const __attribute__((address_space(1))) void*)(g),                              \
    (__attribute__((address_space(3))) void*)(l), 16, 0, 0)

// ---------------- weight transpose+convert: fp32 [K][N] -> bf16 [N][K] ----------
__global__ __launch_bounds__(256) void wtrans_kernel(const float* __restrict__ in,
                                                     bf16* __restrict__ out,
                                                     int K, int N) {
  __shared__ float tile[32][33];
  int tx = threadIdx.x, ty = threadIdx.y;
  int n0 = blockIdx.x * 32, k0 = blockIdx.y * 32;
#pragma unroll
  for (int i = 0; i < 32; i += 8)
    tile[ty + i][tx] = in[(size_t)(k0 + ty + i) * N + (n0 + tx)];
  __syncthreads();
#pragma unroll
  for (int i = 0; i < 32; i += 8)
    out[(size_t)(n0 + ty + i) * K + (k0 + tx)] = __float2bfloat16(tile[tx][ty + i]);
}

// ---------------- bf16 transpose, batched, with pitches -------------------------
__global__ __launch_bounds__(256) void btrans_kernel(const bf16* __restrict__ in,
                                                     int ldin, size_t sIn,
                                                     bf16* __restrict__ out,
                                                     int ldout, size_t sOut) {
  __shared__ bf16 tile[32][33];
  int tx = threadIdx.x, ty = threadIdx.y;
  int c0 = blockIdx.x * 32, r0 = blockIdx.y * 32;
  size_t bi = sIn * blockIdx.z, bo = sOut * blockIdx.z;
#pragma unroll
  for (int i = 0; i < 32; i += 8)
    tile[ty + i][tx] = in[bi + (size_t)(r0 + ty + i) * ldin + (c0 + tx)];
  __syncthreads();
#pragma unroll
  for (int i = 0; i < 32; i += 8)
    out[bo + (size_t)(c0 + ty + i) * ldout + (r0 + tx)] = tile[tx][ty + i];
}

// ---------------- LayerNorm fp32 -> bf16, D=1024, one block(256)/row ------------
__global__ __launch_bounds__(256) void ln_kernel(const float* __restrict__ x,
                                                 const float* __restrict__ g,
                                                 const float* __restrict__ b,
                                                 bf16* __restrict__ out) {
  const int D = 1024;
  size_t row = blockIdx.x;
  int t = threadIdx.x;
  float4 v = ((const float4*)(x + row * D))[t];
  float s  = v.x + v.y + v.z + v.w;
  float ss = v.x * v.x + v.y * v.y + v.z * v.z + v.w * v.w;
#pragma unroll
  for (int off = 32; off > 0; off >>= 1) {
    s  += __shfl_xor(s, off);
    ss += __shfl_xor(ss, off);
  }
  __shared__ float rs[4], rss[4];
  int wv = t >> 6;
  if ((t & 63) == 0) { rs[wv] = s; rss[wv] = ss; }
  __syncthreads();
  s  = rs[0] + rs[1] + rs[2] + rs[3];
  ss = rss[0] + rss[1] + rss[2] + rss[3];
  float mu  = s * (1.f / D);
  float inv = rsqrtf(ss * (1.f / D) - mu * mu + 1e-5f);
  float4 gv = ((const float4*)g)[t];
  float4 bv = ((const float4*)b)[t];
  ushort4 o;
  o.x = f2bf((v.x - mu) * inv * gv.x + bv.x);
  o.y = f2bf((v.y - mu) * inv * gv.y + bv.y);
  o.z = f2bf((v.z - mu) * inv * gv.z + bv.z);
  o.w = f2bf((v.w - mu) * inv * gv.w + bv.w);
  ((ushort4*)(out + row * D))[t] = o;
}

// ---------------- softmax: fp32 row (2048) -> bf16 written in place -------------
__global__ __launch_bounds__(256) void softmax_kernel(float* sc) {
  const int S = 2048;
  float* p = sc + (size_t)blockIdx.x * S;
  int t = threadIdx.x;
  float4 v0 = ((const float4*)p)[2 * t];
  float4 v1 = ((const float4*)p)[2 * t + 1];
  float f[8] = {v0.x, v0.y, v0.z, v0.w, v1.x, v1.y, v1.z, v1.w};
  float m = f[0];
#pragma unroll
  for (int j = 1; j < 8; ++j) m = fmaxf(m, f[j]);
#pragma unroll
  for (int off = 32; off > 0; off >>= 1) m = fmaxf(m, __shfl_xor(m, off));
  __shared__ float r1[4], r2[4];
  int wv = t >> 6;
  if ((t & 63) == 0) r1[wv] = m;
  __syncthreads();
  m = fmaxf(fmaxf(r1[0], r1[1]), fmaxf(r1[2], r1[3]));
  float s = 0.f;
#pragma unroll
  for (int j = 0; j < 8; ++j) { f[j] = __expf(f[j] - m); s += f[j]; }
#pragma unroll
  for (int off = 32; off > 0; off >>= 1) s += __shfl_xor(s, off);
  if ((t & 63) == 0) r2[wv] = s;
  __syncthreads();
  s = r2[0] + r2[1] + r2[2] + r2[3];
  float inv = 1.f / s;
  unsigned u0 = f2bf(f[0] * inv), u1 = f2bf(f[1] * inv);
  unsigned u2 = f2bf(f[2] * inv), u3 = f2bf(f[3] * inv);
  unsigned u4 = f2bf(f[4] * inv), u5 = f2bf(f[5] * inv);
  unsigned u6 = f2bf(f[6] * inv), u7 = f2bf(f[7] * inv);
  uint4 o;
  o.x = u0 | (u1 << 16);
  o.y = u2 | (u3 << 16);
  o.z = u4 | (u5 << 16);
  o.w = u6 | (u7 << 16);
  ((uint4*)p)[t] = o;
}

// ---------------- 8-phase GEMM: C = alpha*(A[M,K] @ BT[N,K]^T) (+bias)(+gelu)(+res)
// BM=256, BN=NF*64, BK=64. 8 waves (2Mx4N). K-split half-tiles (A_k0,A_k1,B_k0,
// B_k1; 16KB / NF*4KB each), double-buffered. 4 phases/K-tile, each: {ds_read
// 4-8 b128 | stage 1 half-tile (GLL w16) | barrier | lgkm0+SB | prio1 16/8 MFMA
// prio0 | barrier}. Counted vmcnt(VM) at p1/p3 only (5 half-tiles in flight,
// never drained). Tail issues dummy GLLs to scratch so vmcnt counts stay uniform.
// XOR-swizzle both-sides (global src pre-swizzled, ds_read swizzled): 2-way only.
template <int NF, bool OUT_BF16, bool HAS_BIAS, bool HAS_RES, bool GELU>
__global__ __launch_bounds__(512, 2) void gemm8p(
    const bf16* __restrict__ A, int lda, size_t sA,
    const bf16* __restrict__ BT, int ldb, size_t sB,
    void* Cv, size_t sC,
    const float* __restrict__ bias, const float* res,
    int N, int K, float alpha, int gx, int gy) {
  constexpr int BN = NF * 64;
  constexpr int LB = NF / 2;      // B-half GLLs per thread (A-half = 2)
  constexpr int VM = 4 + 3 * LB;  // counted vmcnt: 10 (NF=4) / 7 (NF=2)
  constexpr int BSLOT = BN * 64;  // bytes per B half-slot
  __shared__ char lds[65536 + 4 * BSLOT + 1024];
  char* const ldsA = lds;
  char* const ldsB = lds + 65536;
  char* const ldsScr = lds + 65536 + 4 * BSLOT;

  const int tid = threadIdx.x;
  const int lane = tid & 63;
  const int wave = tid >> 6;
  const int wm = wave >> 2, wn = wave & 3;
  const int lr = lane & 15, lq = lane >> 4;

  int id = blockIdx.x;
  const int nwg = gridDim.x;
  if ((nwg & 7) == 0) id = (id & 7) * (nwg >> 3) + (id >> 3);  // XCD swizzle
  const int bx = id % gx;
  const int rem = id / gx;
  const int by = rem % gy;
  const int bz = rem / gy;
  const int m0 = by * 256, n0 = bx * BN;

  // staging: thread covers row wrow (g0) / wrow+128 (g1), 16B chunk (lane&3),
  // source column pre-swizzled so linear LDS + swizzled read = consistent XOR
  const int wrow = wave * 16 + (lane >> 2);
  const int swzc = ((lane & 3) ^ ((lane >> 2) & 3)) * 8;
  const bf16* gA = A + sA * bz + (size_t)(m0 + wrow) * lda + swzc;
  const bf16* gB = BT + sB * bz + (size_t)(n0 + wrow) * ldb + swzc;

  const int nk = K >> 6;

  const int aBase = (wm * 128 + lr) * 64 + ((lq ^ (lr & 3)) << 4);
  const int bBase = (wn * (NF * 16) + lr) * 64 + ((lq ^ (lr & 3)) << 4);

  auto stA = [&](int tau, int h) {
    const int tc = tau < nk ? tau : nk - 1;
    const bf16* s = gA + (size_t)tc * 64 + h * 32;
    if (tau < nk) {
      char* d = ldsA + (((tau & 1) * 2 + h) << 14) + tid * 16;
      GLL(s, d);
      GLL(s + (size_t)128 * lda, d + 8192);
    } else {  // dummy: keep per-wave vmcnt issue counts uniform
      char* d = ldsScr + (lane << 4);
      GLL(s, d);
      GLL(s, d);
    }
  };
  auto stB = [&](int tau, int h) {
    const int tc = tau < nk ? tau : nk - 1;
    const bf16* s = gB + (size_t)tc * 64 + h * 32;
    if (tau < nk) {
      char* d = ldsB + ((tau & 1) * 2 + h) * BSLOT + tid * 16;
      GLL(s, d);
      if constexpr (NF == 4) GLL(s + (size_t)128 * ldb, d + 8192);
    } else {
      char* d = ldsScr + (lane << 4);
      GLL(s, d);
      if constexpr (NF == 4) GLL(s, d);
    }
  };

  floatx4 acc[8][NF] = {};

  // prologue: issue order mirrors steady-state phase stream (t-2,p1)..(t-1,p3)
  stB(0, 0); stA(0, 0); stB(0, 1); stA(0, 1);
  stB(1, 0); stA(1, 0); stB(1, 1);
  asm volatile("s_waitcnt vmcnt(%0)" ::"i"(VM) : "memory");
  __builtin_amdgcn_s_barrier();

  for (int t = 0; t < nk; ++t) {
    const char* Ak0 = ldsA + (((t & 1) * 2 + 0) << 14);
    const char* Ak1 = ldsA + (((t & 1) * 2 + 1) << 14);
    const char* Bk0 = ldsB + ((t & 1) * 2 + 0) * BSLOT;
    const char* Bk1 = ldsB + ((t & 1) * 2 + 1) * BSLOT;

    // ---- p0: (kk0, mq0)
    short8 b0[NF], a0[4];
#pragma unroll
    for (int ni = 0; ni < NF; ++ni) b0[ni] = *(const short8*)(Bk0 + bBase + ni * 1024);
#pragma unroll
    for (int mi = 0; mi < 4; ++mi) a0[mi] = *(const short8*)(Ak0 + aBase + mi * 1024);
    stA(t + 1, 1);
    __builtin_amdgcn_s_barrier();
    asm volatile("s_waitcnt lgkmcnt(0)" ::: "memory");
    __builtin_amdgcn_sched_barrier(0);
    __builtin_amdgcn_s_setprio(1);
#pragma unroll
    for (int mi = 0; mi < 4; ++mi)
#pragma unroll
      for (int ni = 0; ni < NF; ++ni)
        acc[mi][ni] = __builtin_amdgcn_mfma_f32_16x16x32_bf16(a0[mi], b0[ni], acc[mi][ni], 0, 0, 0);
    __builtin_amdgcn_s_setprio(0);
    __builtin_amdgcn_s_barrier();

    // ---- p1: (kk0, mq1)
    short8 a1[4];
#pragma unroll
    for (int mi = 0; mi < 4; ++mi) a1[mi] = *(const short8*)(Ak0 + aBase + 4096 + mi * 1024);
    stB(t + 2, 0);
    __builtin_amdgcn_s_barrier();
    asm volatile("s_waitcnt lgkmcnt(0)" ::: "memory");
    __builtin_amdgcn_sched_barrier(0);
    __builtin_amdgcn_s_setprio(1);
#pragma unroll
    for (int mi = 0; mi < 4; ++mi)
#pragma unroll
      for (int ni = 0; ni < NF; ++ni)
        acc[4 + mi][ni] = __builtin_amdgcn_mfma_f32_16x16x32_bf16(a1[mi], b0[ni], acc[4 + mi][ni], 0, 0, 0);
    __builtin_amdgcn_s_setprio(0);
    asm volatile("s_waitcnt vmcnt(%0)" ::"i"(VM) : "memory");
    __builtin_amdgcn_s_barrier();

    // ---- p2: (kk1, mq0)
    short8 b1[NF], a2[4];
#pragma unroll
    for (int ni = 0; ni < NF; ++ni) b1[ni] = *(const short8*)(Bk1 + bBase + ni * 1024);
#pragma unroll
    for (int mi = 0; mi < 4; ++mi) a2[mi] = *(const short8*)(Ak1 + aBase + mi * 1024);
    stA(t + 2, 0);
    __builtin_amdgcn_s_barrier();
    asm volatile("s_waitcnt lgkmcnt(0)" ::: "memory");
    __builtin_amdgcn_sched_barrier(0);
    __builtin_amdgcn_s_setprio(1);
#pragma unroll
    for (int mi = 0; mi < 4; ++mi)
#pragma unroll
      for (int ni = 0; ni < NF; ++ni)
        acc[mi][ni] = __builtin_amdgcn_mfma_f32_16x16x32_bf16(a2[mi], b1[ni], acc[mi][ni], 0, 0, 0);
    __builtin_amdgcn_s_setprio(0);
    __builtin_amdgcn_s_barrier();

    // ---- p3: (kk1, mq1)
    short8 a3[4];
#pragma unroll
    for (int mi = 0; mi < 4; ++mi) a3[mi] = *(const short8*)(Ak1 + aBase + 4096 + mi * 1024);
    stB(t + 2, 1);
    __builtin_amdgcn_s_barrier();
    asm volatile("s_waitcnt lgkmcnt(0)" ::: "memory");
    __builtin_amdgcn_sched_barrier(0);
    __builtin_amdgcn_s_setprio(1);
#pragma unroll
    for (int mi = 0; mi < 4; ++mi)
#pragma unroll
      for (int ni = 0; ni < NF; ++ni)
        acc[4 + mi][ni] = __builtin_amdgcn_mfma_f32_16x16x32_bf16(a3[mi], b1[ni], acc[4 + mi][ni], 0, 0, 0);
    __builtin_amdgcn_s_setprio(0);
    asm volatile("s_waitcnt vmcnt(%0)" ::"i"(VM) : "memory");
    __builtin_amdgcn_s_barrier();
  }
  asm volatile("s_waitcnt vmcnt(0)" ::: "memory");  // drain dummies before exit

  // epilogue: C/D frag map col=lane&15, row=(lane>>4)*4+r [m89-verified]
  float* Cf = (float*)Cv;
  bf16* Cb = (bf16*)Cv;
  const size_t cb = sC * bz;
#pragma unroll
  for (int mi = 0; mi < 8; ++mi) {
    const int row = m0 + wm * 128 + mi * 16 + lq * 4;
#pragma unroll
    for (int ni = 0; ni < NF; ++ni) {
      const int col = n0 + wn * (NF * 16) + ni * 16 + lr;
      const float bb = HAS_BIAS ? bias[col] : 0.f;
#pragma unroll
      for (int r = 0; r < 4; ++r) {
        float val = acc[mi][ni][r] * alpha + bb;
        if (GELU) val = 0.5f * val * (1.f + erff(val * 0.70710678118654752f));
        if (HAS_RES) val += res[(size_t)(row + r) * N + col];
        const size_t idx = cb + (size_t)(row + r) * N + col;
        if (OUT_BF16) Cb[idx] = __float2bfloat16(val);
        else Cf[idx] = val;
      }
    }
  }
}

extern "C" void kernel_launch(void* const* d_in, const int* in_sizes, int n_in,
                              void* d_out, int out_size, void* d_ws, size_t ws_size,
                              hipStream_t stream) {
  const int B = 4, S = 2048, D = 1024, DFF = 4096;
  const int M = B * S;
  const float* x   = (const float*)d_in[0];
  const float* wq  = (const float*)d_in[1];
  const float* bq  = (const float*)d_in[2];
  const float* wk  = (const float*)d_in[3];
  const float* bk  = (const float*)d_in[4];
  const float* wv  = (const float*)d_in[5];
  const float* bv  = (const float*)d_in[6];
  const float* wo  = (const float*)d_in[7];
  const float* bo  = (const float*)d_in[8];
  const float* w1  = (const float*)d_in[9];
  const float* b1  = (const float*)d_in[10];
  const float* w2  = (const float*)d_in[11];
  const float* b2  = (const float*)d_in[12];
  const float* g1  = (const float*)d_in[13];
  const float* be1 = (const float*)d_in[14];
  const float* g2  = (const float*)d_in[15];
  const float* be2 = (const float*)d_in[16];
  float* out = (float*)d_out;

  // workspace arena:
  //  0-6 wqkvT  6-8 woT  8-16 w1T  16-24 w2T  24 bqkv  25-41 h (bf16 MxD)
  //  41-89 qkv (bf16 Mx3072) / later hidden (bf16 MxDFF, 41-105)
  //  89+ per-chunk: vT (4c MB) then scores fp32 (16c MB)
  char* wsb = (char*)d_ws;
  const size_t MB1 = 1ull << 20;
  bf16* wqkvT = (bf16*)(wsb + 0 * MB1);
  bf16* woT   = (bf16*)(wsb + 6 * MB1);
  bf16* w1T   = (bf16*)(wsb + 8 * MB1);
  bf16* w2T   = (bf16*)(wsb + 16 * MB1);
  float* bqkv = (float*)(wsb + 24 * MB1);
  bf16* h     = (bf16*)(wsb + 25 * MB1);
  bf16* qkv   = (bf16*)(wsb + 41 * MB1);
  bf16* hidden = (bf16*)(wsb + 41 * MB1);
  char* attn  = wsb + 89 * MB1;

  int chunk = 1;
  if (ws_size > 89 * MB1) {
    size_t c = (ws_size - 89 * MB1) / (20 * MB1);
    chunk = (int)(c > 4 ? 4 : (c < 1 ? 1 : c));
  }
  bf16* vTc = (bf16*)attn;                              // [c][D][S]
  float* sc = (float*)(attn + (size_t)chunk * 4 * MB1); // [c][S][S] fp32

  dim3 tb(32, 8);
  wtrans_kernel<<<dim3(32, 32), tb, 0, stream>>>(wq, wqkvT, D, D);
  wtrans_kernel<<<dim3(32, 32), tb, 0, stream>>>(wk, wqkvT + (size_t)1024 * 1024, D, D);
  wtrans_kernel<<<dim3(32, 32), tb, 0, stream>>>(wv, wqkvT + (size_t)2048 * 1024, D, D);
  wtrans_kernel<<<dim3(32, 32), tb, 0, stream>>>(wo, woT, D, D);
  wtrans_kernel<<<dim3(128, 32), tb, 0, stream>>>(w1, w1T, D, DFF);
  wtrans_kernel<<<dim3(32, 128), tb, 0, stream>>>(w2, w2T, DFF, D);
  hipMemcpyAsync(bqkv, bq, 4096, hipMemcpyDeviceToDevice, stream);
  hipMemcpyAsync(bqkv + 1024, bk, 4096, hipMemcpyDeviceToDevice, stream);
  hipMemcpyAsync(bqkv + 2048, bv, 4096, hipMemcpyDeviceToDevice, stream);

  // h = LN1(x)
  ln_kernel<<<M, 256, 0, stream>>>(x, g1, be1, h);

  // qkv = h @ [wq|wk|wv] + biases  (BN=128 -> 768 blocks = 3/CU)
  gemm8p<2, true, true, false, false><<<24 * 32, 512, 0, stream>>>(
      h, D, 0, wqkvT, D, 0, qkv, 0, bqkv, nullptr, 3072, D, 1.f, 24, 32);

  for (int b0 = 0; b0 < B; b0 += chunk) {
    int c = (B - b0 < chunk) ? (B - b0) : chunk;
    btrans_kernel<<<dim3(32, 64, c), tb, 0, stream>>>(
        qkv + (size_t)b0 * S * 3072 + 2048, 3072, (size_t)S * 3072,
        vTc, S, (size_t)D * S);
    // scores = q @ k^T * 0.125 (fp32, BN=256)
    gemm8p<4, false, false, false, false><<<64 * c, 512, 0, stream>>>(
        qkv + (size_t)b0 * S * 3072, 3072, (size_t)S * 3072,
        qkv + (size_t)b0 * S * 3072 + 1024, 3072, (size_t)S * 3072,
        sc, (size_t)S * S, nullptr, nullptr, S, D, 0.125f, 8, 8);
    softmax_kernel<<<c * S, 256, 0, stream>>>(sc);
    // ctx = probs @ vT^T (probs bf16 in-place over fp32 rows, pitch 2S; BN=128)
    gemm8p<2, true, false, false, false><<<64 * c, 512, 0, stream>>>(
        (const bf16*)sc, 2 * S, (size_t)S * 2 * S,
        vTc, S, (size_t)D * S,
        h + (size_t)b0 * S * D, (size_t)S * D, nullptr, nullptr, D, S, 1.f, 8, 8);
  }

  // x2 = ctx @ wo + bo + x -> d_out (fp32)
  gemm8p<2, false, true, true, false><<<8 * 32, 512, 0, stream>>>(
      h, D, 0, woT, D, 0, out, 0, bo, x, D, D, 1.f, 8, 32);

  // h = LN2(x2)
  ln_kernel<<<M, 256, 0, stream>>>(out, g2, be2, h);

  // hidden = gelu(h @ w1 + b1)  (BN=256 -> 512 blocks)
  gemm8p<4, true, true, false, true><<<16 * 32, 512, 0, stream>>>(
      h, D, 0, w1T, D, 0, hidden, 0, b1, nullptr, DFF, D, 1.f, 16, 32);

  // out = hidden @ w2 + b2 + x2 (in-place residual)
  gemm8p<2, false, true, true, false><<<8 * 32, 512, 0, stream>>>(
      hidden, DFF, 0, w2T, DFF, 0, out, 0, b2, out, D, DFF, 1.f, 8, 32);
}

// Round 4
// 473.421 us; speedup vs baseline: 1.4328x; 1.0393x over previous
//
#include <hip/hip_runtime.h>
#include <hip/hip_bf16.h>

typedef __hip_bfloat16 bf16;
typedef __attribute__((ext_vector_type(8))) short short8;
typedef __attribute__((ext_vector_type(4))) float floatx4;

__device__ __forceinline__ unsigned short f2bf(float x) {
  unsigned u = __builtin_bit_cast(unsigned, x);
  unsigned r = (u + 0x7fffu + ((u >> 16) & 1u)) >> 16;
  return (unsigned short)r;
}

#define GLL(g, l) __builtin_amdgcn_global_load_lds(                                  \
    (const __attribute__((address_space(1))) void*)(g),                              \
    (__attribute__((address_space(3))) void*)(l), 16, 0, 0)

template <int N> __device__ __forceinline__ void vmwait() {
  asm volatile("s_waitcnt vmcnt(%0)" ::"i"(N) : "memory");
}

// ---------------- weight transpose+convert: fp32 [K][N] -> bf16 [N][K] ----------
__global__ __launch_bounds__(256) void wtrans_kernel(const float* __restrict__ in,
                                                     bf16* __restrict__ out,
                                                     int K, int N) {
  __shared__ float tile[32][33];
  int tx = threadIdx.x, ty = threadIdx.y;
  int n0 = blockIdx.x * 32, k0 = blockIdx.y * 32;
#pragma unroll
  for (int i = 0; i < 32; i += 8)
    tile[ty + i][tx] = in[(size_t)(k0 + ty + i) * N + (n0 + tx)];
  __syncthreads();
#pragma unroll
  for (int i = 0; i < 32; i += 8)
    out[(size_t)(n0 + ty + i) * K + (k0 + tx)] = __float2bfloat16(tile[tx][ty + i]);
}

// ---------------- LayerNorm fp32 -> bf16, D=1024, one block(256)/row ------------
__global__ __launch_bounds__(256) void ln_kernel(const float* __restrict__ x,
                                                 const float* __restrict__ g,
                                                 const float* __restrict__ b,
                                                 bf16* __restrict__ out) {
  const int D = 1024;
  size_t row = blockIdx.x;
  int t = threadIdx.x;
  float4 v = ((const float4*)(x + row * D))[t];
  float s  = v.x + v.y + v.z + v.w;
  float ss = v.x * v.x + v.y * v.y + v.z * v.z + v.w * v.w;
#pragma unroll
  for (int off = 32; off > 0; off >>= 1) {
    s  += __shfl_xor(s, off);
    ss += __shfl_xor(ss, off);
  }
  __shared__ float rs[4], rss[4];
  int wv = t >> 6;
  if ((t & 63) == 0) { rs[wv] = s; rss[wv] = ss; }
  __syncthreads();
  s  = rs[0] + rs[1] + rs[2] + rs[3];
  ss = rss[0] + rss[1] + rss[2] + rss[3];
  float mu  = s * (1.f / D);
  float inv = rsqrtf(ss * (1.f / D) - mu * mu + 1e-5f);
  float4 gv = ((const float4*)g)[t];
  float4 bv = ((const float4*)b)[t];
  ushort4 o;
  o.x = f2bf((v.x - mu) * inv * gv.x + bv.x);
  o.y = f2bf((v.y - mu) * inv * gv.y + bv.y);
  o.z = f2bf((v.z - mu) * inv * gv.z + bv.z);
  o.w = f2bf((v.w - mu) * inv * gv.w + bv.w);
  ((ushort4*)(out + row * D))[t] = o;
}

// ---------------- softmax: fp32 row (2048) -> bf16 written in place -------------
__global__ __launch_bounds__(256) void softmax_kernel(float* sc) {
  const int S = 2048;
  float* p = sc + (size_t)blockIdx.x * S;
  int t = threadIdx.x;
  float4 v0 = ((const float4*)p)[2 * t];
  float4 v1 = ((const float4*)p)[2 * t + 1];
  float f[8] = {v0.x, v0.y, v0.z, v0.w, v1.x, v1.y, v1.z, v1.w};
  float m = f[0];
#pragma unroll
  for (int j = 1; j < 8; ++j) m = fmaxf(m, f[j]);
#pragma unroll
  for (int off = 32; off > 0; off >>= 1) m = fmaxf(m, __shfl_xor(m, off));
  __shared__ float r1[4], r2[4];
  int wv = t >> 6;
  if ((t & 63) == 0) r1[wv] = m;
  __syncthreads();
  m = fmaxf(fmaxf(r1[0], r1[1]), fmaxf(r1[2], r1[3]));
  float s = 0.f;
#pragma unroll
  for (int j = 0; j < 8; ++j) { f[j] = __expf(f[j] - m); s += f[j]; }
#pragma unroll
  for (int off = 32; off > 0; off >>= 1) s += __shfl_xor(s, off);
  if ((t & 63) == 0) r2[wv] = s;
  __syncthreads();
  s = r2[0] + r2[1] + r2[2] + r2[3];
  float inv = 1.f / s;
  unsigned u0 = f2bf(f[0] * inv), u1 = f2bf(f[1] * inv);
  unsigned u2 = f2bf(f[2] * inv), u3 = f2bf(f[3] * inv);
  unsigned u4 = f2bf(f[4] * inv), u5 = f2bf(f[5] * inv);
  unsigned u6 = f2bf(f[6] * inv), u7 = f2bf(f[7] * inv);
  uint4 o;
  o.x = u0 | (u1 << 16);
  o.y = u2 | (u3 << 16);
  o.z = u4 | (u5 << 16);
  o.w = u6 | (u7 << 16);
  ((uint4*)p)[t] = o;
}

// ---------------- quadrant-phase GEMM: C = alpha*(A @ BT^T) (+bias)(+gelu)(+res)
// BM=256, BN=NF*64, BK=64; 8 waves (2Mx4N). LDS rows are 128B (full BK), halves
// are M-halves (A) / N-halves (B), 16/8KB each, double-buffered. 4 phases per
// K-tile = C-quadrants (m0n0,m0n1,m1n1,m1n0) with frag reuse; each phase stages
// ONE half of tile t+1 and ends with {counted vmcnt; s_barrier}. Waits never 0.
// XOR swizzle (row&7)<<4 applied on both sides (GLL src pre-swizzled, ds_read
// swizzled) -> 2-way conflicts (free). VTR: also emit V^T for attention.
template <int NF, bool OUT_BF16, bool HAS_BIAS, bool HAS_RES, bool GELU, bool VTR>
__global__ __launch_bounds__(512, 2) void gemm4q(
    const bf16* __restrict__ A, int lda, size_t sA,
    const bf16* __restrict__ BT, int ldb, size_t sB,
    void* Cv, size_t sC,
    const float* __restrict__ bias, const float* res, bf16* vtr,
    int N, int K, float alpha, int gx, int gy) {
  constexpr int BN = NF * 64;
  constexpr int NI = NF / 2;               // B frags per quadrant per wave
  constexpr int BHALF = NF == 4 ? 16384 : 8192;
  constexpr int W_A = 4;                    // end-p0 wait (both NF)
  constexpr int W_B = NF == 4 ? 4 : 3;      // end-p1 / end-p3 / prologue wait
  __shared__ __align__(16) char lds[65536 + (NF == 4 ? 65536 : 32768)];
  char* const ldsA = lds;
  char* const ldsB = lds + 65536;

  const int tid = threadIdx.x;
  const int lane = tid & 63;
  const int wave = tid >> 6;
  const int wm = wave >> 2, wn = wave & 3;
  const int lr = lane & 15, lq = lane >> 4;

  int id = blockIdx.x;
  const int nwg = gridDim.x;
  if ((nwg & 7) == 0) id = (id & 7) * (nwg >> 3) + (id >> 3);  // XCD swizzle
  const int bx = id % gx;
  const int rem = id / gx;
  const int by = rem % gy;
  const int bz = rem / gy;
  const int m0 = by * 256, n0 = bx * BN;

  // staging map: thread -> (row = tid>>3, 16B chunk = tid&7); source column
  // pre-swizzled so linear GLL dest + XOR'd ds_read are consistent
  const int srow = tid >> 3;
  const int schunk = ((tid & 7) ^ (srow & 7)) * 8;
  const bf16* gA = A + sA * bz + (size_t)(m0 + srow) * lda + schunk;
  const bf16* gB = BT + sB * bz + (size_t)(n0 + srow) * ldb + schunk;

  const int nk = K >> 6;

  auto stA = [&](int tt, int h) {
    if (tt < nk) {
      const bf16* s = gA + (size_t)(h * 128) * lda + (size_t)tt * 64;
      char* d = ldsA + (((tt & 1) * 2 + h) << 14) + tid * 16;
      GLL(s, d);
      GLL(s + (size_t)64 * lda, d + 8192);
    }
  };
  auto stB = [&](int tt, int h) {
    if (tt < nk) {
      const bf16* s = gB + (size_t)(h * (BN / 2)) * ldb + (size_t)tt * 64;
      char* d = ldsB + ((tt & 1) * 2 + h) * BHALF + tid * 16;
      GLL(s, d);
      if constexpr (NF == 4) GLL(s + (size_t)64 * ldb, d + 8192);
    }
  };

  // ds_read bases: row*128 + ((chunk ^ (row&7))<<4); kk=1 flips chunk bit2 (^64)
  const int aB0 = (wm * 64 + lr) * 128 + ((lq ^ (lr & 7)) << 4);
  const int aB1 = aB0 ^ 64;
  const int bRow = (NF == 4) ? (wn * 32 + lr) : (wn * 16 + lr);
  const int bB0 = bRow * 128 + ((lq ^ (lr & 7)) << 4);
  const int bB1 = bB0 ^ 64;

  floatx4 acc[2][2][4][NI] = {};

  // prologue: stage tile 0 (A0,B0,B1,A1 - in-loop issue order), wait, barrier
  stA(0, 0); stB(0, 0); stB(0, 1); stA(0, 1);
  vmwait<W_B>();
  __builtin_amdgcn_s_barrier();

  for (int t = 0; t < nk; ++t) {
    const char* As0 = ldsA + (((t & 1) * 2 + 0) << 14);
    const char* As1 = ldsA + (((t & 1) * 2 + 1) << 14);
    const char* Bs0 = ldsB + ((t & 1) * 2 + 0) * BHALF;
    const char* Bs1 = ldsB + ((t & 1) * 2 + 1) * BHALF;
    short8 a0[4], a1[4], b0[NI], b1[NI];

    // ===== p0: quadrant (m0, n0) — read A0 + B0; stage A0(t+1)
#pragma unroll
    for (int mi = 0; mi < 4; ++mi) {
      a0[mi] = *(const short8*)(As0 + aB0 + mi * 2048);
      a1[mi] = *(const short8*)(As0 + aB1 + mi * 2048);
    }
#pragma unroll
    for (int ni = 0; ni < NI; ++ni) {
      b0[ni] = *(const short8*)(Bs0 + bB0 + ni * 2048);
      b1[ni] = *(const short8*)(Bs0 + bB1 + ni * 2048);
    }
    stA(t + 1, 0);
    asm volatile("s_waitcnt lgkmcnt(0)" ::: "memory");
    __builtin_amdgcn_sched_barrier(0);
    __builtin_amdgcn_s_setprio(1);
#pragma unroll
    for (int mi = 0; mi < 4; ++mi)
#pragma unroll
      for (int ni = 0; ni < NI; ++ni)
        acc[0][0][mi][ni] = __builtin_amdgcn_mfma_f32_16x16x32_bf16(a0[mi], b0[ni], acc[0][0][mi][ni], 0, 0, 0);
#pragma unroll
    for (int mi = 0; mi < 4; ++mi)
#pragma unroll
      for (int ni = 0; ni < NI; ++ni)
        acc[0][0][mi][ni] = __builtin_amdgcn_mfma_f32_16x16x32_bf16(a1[mi], b1[ni], acc[0][0][mi][ni], 0, 0, 0);
    __builtin_amdgcn_s_setprio(0);
    vmwait<W_A>();
    __builtin_amdgcn_s_barrier();

    // ===== p1: quadrant (m0, n1) — A reused; read B1; stage B0(t+1)
#pragma unroll
    for (int ni = 0; ni < NI; ++ni) {
      b0[ni] = *(const short8*)(Bs1 + bB0 + ni * 2048);
      b1[ni] = *(const short8*)(Bs1 + bB1 + ni * 2048);
    }
    stB(t + 1, 0);
    asm volatile("s_waitcnt lgkmcnt(0)" ::: "memory");
    __builtin_amdgcn_sched_barrier(0);
    __builtin_amdgcn_s_setprio(1);
#pragma unroll
    for (int mi = 0; mi < 4; ++mi)
#pragma unroll
      for (int ni = 0; ni < NI; ++ni)
        acc[0][1][mi][ni] = __builtin_amdgcn_mfma_f32_16x16x32_bf16(a0[mi], b0[ni], acc[0][1][mi][ni], 0, 0, 0);
#pragma unroll
    for (int mi = 0; mi < 4; ++mi)
#pragma unroll
      for (int ni = 0; ni < NI; ++ni)
        acc[0][1][mi][ni] = __builtin_amdgcn_mfma_f32_16x16x32_bf16(a1[mi], b1[ni], acc[0][1][mi][ni], 0, 0, 0);
    __builtin_amdgcn_s_setprio(0);
    vmwait<W_B>();
    __builtin_amdgcn_s_barrier();

    // ===== p2: quadrant (m1, n1) — B reused; read A1; stage B1(t+1)
#pragma unroll
    for (int mi = 0; mi < 4; ++mi) {
      a0[mi] = *(const short8*)(As1 + aB0 + mi * 2048);
      a1[mi] = *(const short8*)(As1 + aB1 + mi * 2048);
    }
    stB(t + 1, 1);
    asm volatile("s_waitcnt lgkmcnt(0)" ::: "memory");
    __builtin_amdgcn_sched_barrier(0);
    __builtin_amdgcn_s_setprio(1);
#pragma unroll
    for (int mi = 0; mi < 4; ++mi)
#pragma unroll
      for (int ni = 0; ni < NI; ++ni)
        acc[1][1][mi][ni] = __builtin_amdgcn_mfma_f32_16x16x32_bf16(a0[mi], b0[ni], acc[1][1][mi][ni], 0, 0, 0);
#pragma unroll
    for (int mi = 0; mi < 4; ++mi)
#pragma unroll
      for (int ni = 0; ni < NI; ++ni)
        acc[1][1][mi][ni] = __builtin_amdgcn_mfma_f32_16x16x32_bf16(a1[mi], b1[ni], acc[1][1][mi][ni], 0, 0, 0);
    __builtin_amdgcn_s_setprio(0);
    __builtin_amdgcn_s_barrier();

    // ===== p3: quadrant (m1, n0) — A reused; re-read B0; stage A1(t+1)
#pragma unroll
    for (int ni = 0; ni < NI; ++ni) {
      b0[ni] = *(const short8*)(Bs0 + bB0 + ni * 2048);
      b1[ni] = *(const short8*)(Bs0 + bB1 + ni * 2048);
    }
    stA(t + 1, 1);
    asm volatile("s_waitcnt lgkmcnt(0)" ::: "memory");
    __builtin_amdgcn_sched_barrier(0);
    __builtin_amdgcn_s_setprio(1);
#pragma unroll
    for (int mi = 0; mi < 4; ++mi)
#pragma unroll
      for (int ni = 0; ni < NI; ++ni)
        acc[1][0][mi][ni] = __builtin_amdgcn_mfma_f32_16x16x32_bf16(a0[mi], b0[ni], acc[1][0][mi][ni], 0, 0, 0);
#pragma unroll
    for (int mi = 0; mi < 4; ++mi)
#pragma unroll
      for (int ni = 0; ni < NI; ++ni)
        acc[1][0][mi][ni] = __builtin_amdgcn_mfma_f32_16x16x32_bf16(a1[mi], b1[ni], acc[1][0][mi][ni], 0, 0, 0);
    __builtin_amdgcn_s_setprio(0);
    vmwait<W_B>();
    __builtin_amdgcn_s_barrier();
  }

  // epilogue: C/D frag map col=lane&15, row=(lane>>4)*4+r [m89-verified]
  float* Cf = (float*)Cv;
  bf16* Cb = (bf16*)Cv;
  const size_t cb = sC * bz;
#pragma unroll
  for (int mq = 0; mq < 2; ++mq)
#pragma unroll
    for (int nq = 0; nq < 2; ++nq)
#pragma unroll
      for (int mi = 0; mi < 4; ++mi) {
        const int row = m0 + mq * 128 + wm * 64 + mi * 16 + lq * 4;
#pragma unroll
        for (int ni = 0; ni < NI; ++ni) {
          const int col = n0 + nq * (BN / 2) + wn * (BN / 8) + ni * 16 + lr;
          const float bb = HAS_BIAS ? bias[col] : 0.f;
#pragma unroll
          for (int r = 0; r < 4; ++r) {
            float val = acc[mq][nq][mi][ni][r] * alpha + bb;
            if (GELU) val = 0.5f * val * (1.f + erff(val * 0.70710678118654752f));
            if (HAS_RES) val += res[(size_t)(row + r) * N + col];
            const size_t idx = cb + (size_t)(row + r) * N + col;
            if (OUT_BF16) Cb[idx] = __float2bfloat16(val);
            else Cf[idx] = val;
            if (VTR) {
              if (col >= 2048) {  // V columns: also write V^T [b][col-2048][row%S]
                const int rr = row + r;
                vtr[(((size_t)(rr >> 11) << 10) + (col - 2048)) * 2048 + (rr & 2047)] =
                    __float2bfloat16(val);
              }
            }
          }
        }
      }
}

extern "C" void kernel_launch(void* const* d_in, const int* in_sizes, int n_in,
                              void* d_out, int out_size, void* d_ws, size_t ws_size,
                              hipStream_t stream) {
  const int B = 4, S = 2048, D = 1024, DFF = 4096;
  const int M = B * S;
  const float* x   = (const float*)d_in[0];
  const float* wq  = (const float*)d_in[1];
  const float* bq  = (const float*)d_in[2];
  const float* wk  = (const float*)d_in[3];
  const float* bk  = (const float*)d_in[4];
  const float* wv  = (const float*)d_in[5];
  const float* bv  = (const float*)d_in[6];
  const float* wo  = (const float*)d_in[7];
  const float* bo  = (const float*)d_in[8];
  const float* w1  = (const float*)d_in[9];
  const float* b1  = (const float*)d_in[10];
  const float* w2  = (const float*)d_in[11];
  const float* b2  = (const float*)d_in[12];
  const float* g1  = (const float*)d_in[13];
  const float* be1 = (const float*)d_in[14];
  const float* g2  = (const float*)d_in[15];
  const float* be2 = (const float*)d_in[16];
  float* out = (float*)d_out;

  // workspace arena:
  //  0-6 wqkvT  6-8 woT  8-16 w1T  16-24 w2T  24 bqkv  25-41 h (bf16 MxD)
  //  41-89 qkv (bf16 Mx3072) / later hidden (bf16 MxDFF, 41-105... hidden aliases qkv)
  //  89-105 vT [4][D][S] bf16 (written by QKV epilogue)
  //  105+  scores fp32, chunk*16MB
  char* wsb = (char*)d_ws;
  const size_t MB1 = 1ull << 20;
  bf16* wqkvT = (bf16*)(wsb + 0 * MB1);
  bf16* woT   = (bf16*)(wsb + 6 * MB1);
  bf16* w1T   = (bf16*)(wsb + 8 * MB1);
  bf16* w2T   = (bf16*)(wsb + 16 * MB1);
  float* bqkv = (float*)(wsb + 24 * MB1);
  bf16* h     = (bf16*)(wsb + 25 * MB1);
  bf16* qkv   = (bf16*)(wsb + 41 * MB1);
  bf16* hidden = (bf16*)(wsb + 41 * MB1);
  bf16* vTall = (bf16*)(wsb + 89 * MB1);
  float* sc   = (float*)(wsb + 105 * MB1);

  int chunk = 1;
  if (ws_size > 105 * MB1) {
    size_t c = (ws_size - 105 * MB1) / (16 * MB1);
    chunk = (int)(c > 4 ? 4 : (c < 1 ? 1 : c));
  }

  dim3 tb(32, 8);
  wtrans_kernel<<<dim3(32, 32), tb, 0, stream>>>(wq, wqkvT, D, D);
  wtrans_kernel<<<dim3(32, 32), tb, 0, stream>>>(wk, wqkvT + (size_t)1024 * 1024, D, D);
  wtrans_kernel<<<dim3(32, 32), tb, 0, stream>>>(wv, wqkvT + (size_t)2048 * 1024, D, D);
  wtrans_kernel<<<dim3(32, 32), tb, 0, stream>>>(wo, woT, D, D);
  wtrans_kernel<<<dim3(128, 32), tb, 0, stream>>>(w1, w1T, D, DFF);
  wtrans_kernel<<<dim3(32, 128), tb, 0, stream>>>(w2, w2T, DFF, D);
  hipMemcpyAsync(bqkv, bq, 4096, hipMemcpyDeviceToDevice, stream);
  hipMemcpyAsync(bqkv + 1024, bk, 4096, hipMemcpyDeviceToDevice, stream);
  hipMemcpyAsync(bqkv + 2048, bv, 4096, hipMemcpyDeviceToDevice, stream);

  // h = LN1(x)
  ln_kernel<<<M, 256, 0, stream>>>(x, g1, be1, h);

  // qkv = h @ [wq|wk|wv] + biases; V columns also emitted transposed into vTall
  gemm4q<2, true, true, false, false, true><<<24 * 32, 512, 0, stream>>>(
      h, D, 0, wqkvT, D, 0, qkv, 0, bqkv, nullptr, vTall, 3072, D, 1.f, 24, 32);

  for (int b0 = 0; b0 < B; b0 += chunk) {
    int c = (B - b0 < chunk) ? (B - b0) : chunk;
    // scores = q @ k^T * 0.125 (fp32)
    gemm4q<4, false, false, false, false, false><<<64 * c, 512, 0, stream>>>(
        qkv + (size_t)b0 * S * 3072, 3072, (size_t)S * 3072,
        qkv + (size_t)b0 * S * 3072 + 1024, 3072, (size_t)S * 3072,
        sc, (size_t)S * S, nullptr, nullptr, nullptr, S, D, 0.125f, 8, 8);
    softmax_kernel<<<c * S, 256, 0, stream>>>(sc);
    // ctx = probs @ vT^T (probs bf16 in-place over fp32 rows, pitch 2S)
    gemm4q<2, true, false, false, false, false><<<64 * c, 512, 0, stream>>>(
        (const bf16*)sc, 2 * S, (size_t)S * 2 * S,
        vTall + (size_t)b0 * D * S, S, (size_t)D * S,
        h + (size_t)b0 * S * D, (size_t)S * D, nullptr, nullptr, nullptr, D, S, 1.f, 8, 8);
  }

  // x2 = ctx @ wo + bo + x -> d_out (fp32)
  gemm4q<2, false, true, true, false, false><<<8 * 32, 512, 0, stream>>>(
      h, D, 0, woT, D, 0, out, 0, bo, x, nullptr, D, D, 1.f, 8, 32);

  // h = LN2(x2)
  ln_kernel<<<M, 256, 0, stream>>>(out, g2, be2, h);

  // hidden = gelu(h @ w1 + b1)
  gemm4q<4, true, true, false, true, false><<<16 * 32, 512, 0, stream>>>(
      h, D, 0, w1T, D, 0, hidden, 0, b1, nullptr, nullptr, DFF, D, 1.f, 16, 32);

  // out = hidden @ w2 + b2 + x2 (in-place residual)
  gemm4q<2, false, true, true, false, false><<<8 * 32, 512, 0, stream>>>(
      hidden, DFF, 0, w2T, DFF, 0, out, 0, b2, out, nullptr, D, DFF, 1.f, 8, 32);
}

// Round 6
// 464.223 us; speedup vs baseline: 1.4612x; 1.0198x over previous
//
#include <hip/hip_runtime.h>
#include <hip/hip_bf16.h>

typedef __hip_bfloat16 bf16;
typedef __attribute__((ext_vector_type(8))) short short8;
typedef __attribute__((ext_vector_type(4))) float floatx4;
typedef __attribute__((address_space(3))) char c3;

__device__ __forceinline__ unsigned short f2bf(float x) {
  unsigned u = __builtin_bit_cast(unsigned, x);
  unsigned r = (u + 0x7fffu + ((u >> 16) & 1u)) >> 16;
  return (unsigned short)r;
}

#define GLL(g, l) __builtin_amdgcn_global_load_lds(                                  \
    (const __attribute__((address_space(1))) void*)(g),                              \
    (__attribute__((address_space(3))) void*)(l), 16, 0, 0)

template <int N> __device__ __forceinline__ void vmwait() {
  asm volatile("s_waitcnt vmcnt(%0)" ::"i"(N) : "memory");
}
// inline-asm LDS read: invisible to SIInsertWaitcnts (no conservative vmcnt),
// dataflow via "=v"; rule #18: consumer clusters must follow lgkmcnt(0)+sched_barrier(0)
template <int OFF> __device__ __forceinline__ short8 dsr(unsigned a) {
  short8 r;
  asm volatile("ds_read_b128 %0, %1 offset:%2" : "=v"(r) : "v"(a), "i"(OFF));
  return r;
}
__device__ __forceinline__ void lgkm0_fence() {
  asm volatile("s_waitcnt lgkmcnt(0)" ::: "memory");
  __builtin_amdgcn_sched_barrier(0);
}

// ---------------- weight transpose+convert: fp32 [K][N] -> bf16 [N][K] ----------
__global__ __launch_bounds__(256) void wtrans_kernel(const float* __restrict__ in,
                                                     bf16* __restrict__ out,
                                                     int K, int N) {
  __shared__ float tile[32][33];
  int tx = threadIdx.x, ty = threadIdx.y;
  int n0 = blockIdx.x * 32, k0 = blockIdx.y * 32;
#pragma unroll
  for (int i = 0; i < 32; i += 8)
    tile[ty + i][tx] = in[(size_t)(k0 + ty + i) * N + (n0 + tx)];
  __syncthreads();
#pragma unroll
  for (int i = 0; i < 32; i += 8)
    out[(size_t)(n0 + ty + i) * K + (k0 + tx)] = __float2bfloat16(tile[tx][ty + i]);
}

// ---------------- LayerNorm fp32 -> bf16, D=1024, one block(256)/row ------------
__global__ __launch_bounds__(256) void ln_kernel(const float* __restrict__ x,
                                                 const float* __restrict__ g,
                                                 const float* __restrict__ b,
                                                 bf16* __restrict__ out) {
  const int D = 1024;
  size_t row = blockIdx.x;
  int t = threadIdx.x;
  float4 v = ((const float4*)(x + row * D))[t];
  float s  = v.x + v.y + v.z + v.w;
  float ss = v.x * v.x + v.y * v.y + v.z * v.z + v.w * v.w;
#pragma unroll
  for (int off = 32; off > 0; off >>= 1) {
    s  += __shfl_xor(s, off);
    ss += __shfl_xor(ss, off);
  }
  __shared__ float rs[4], rss[4];
  int wv = t >> 6;
  if ((t & 63) == 0) { rs[wv] = s; rss[wv] = ss; }
  __syncthreads();
  s  = rs[0] + rs[1] + rs[2] + rs[3];
  ss = rss[0] + rss[1] + rss[2] + rss[3];
  float mu  = s * (1.f / D);
  float inv = rsqrtf(ss * (1.f / D) - mu * mu + 1e-5f);
  float4 gv = ((const float4*)g)[t];
  float4 bv = ((const float4*)b)[t];
  ushort4 o;
  o.x = f2bf((v.x - mu) * inv * gv.x + bv.x);
  o.y = f2bf((v.y - mu) * inv * gv.y + bv.y);
  o.z = f2bf((v.z - mu) * inv * gv.z + bv.z);
  o.w = f2bf((v.w - mu) * inv * gv.w + bv.w);
  ((ushort4*)(out + row * D))[t] = o;
}

// ---------------- softmax: fp32 row (2048) -> bf16 written in place -------------
__global__ __launch_bounds__(256) void softmax_kernel(float* sc) {
  const int S = 2048;
  float* p = sc + (size_t)blockIdx.x * S;
  int t = threadIdx.x;
  float4 v0 = ((const float4*)p)[2 * t];
  float4 v1 = ((const float4*)p)[2 * t + 1];
  float f[8] = {v0.x, v0.y, v0.z, v0.w, v1.x, v1.y, v1.z, v1.w};
  float m = f[0];
#pragma unroll
  for (int j = 1; j < 8; ++j) m = fmaxf(m, f[j]);
#pragma unroll
  for (int off = 32; off > 0; off >>= 1) m = fmaxf(m, __shfl_xor(m, off));
  __shared__ float r1[4], r2[4];
  int wv = t >> 6;
  if ((t & 63) == 0) r1[wv] = m;
  __syncthreads();
  m = fmaxf(fmaxf(r1[0], r1[1]), fmaxf(r1[2], r1[3]));
  float s = 0.f;
#pragma unroll
  for (int j = 0; j < 8; ++j) { f[j] = __expf(f[j] - m); s += f[j]; }
#pragma unroll
  for (int off = 32; off > 0; off >>= 1) s += __shfl_xor(s, off);
  if ((t & 63) == 0) r2[wv] = s;
  __syncthreads();
  s = r2[0] + r2[1] + r2[2] + r2[3];
  float inv = 1.f / s;
  unsigned u0 = f2bf(f[0] * inv), u1 = f2bf(f[1] * inv);
  unsigned u2 = f2bf(f[2] * inv), u3 = f2bf(f[3] * inv);
  unsigned u4 = f2bf(f[4] * inv), u5 = f2bf(f[5] * inv);
  unsigned u6 = f2bf(f[6] * inv), u7 = f2bf(f[7] * inv);
  uint4 o;
  o.x = u0 | (u1 << 16);
  o.y = u2 | (u3 << 16);
  o.z = u4 | (u5 << 16);
  o.w = u6 | (u7 << 16);
  ((uint4*)p)[t] = o;
}

// ---------------- quadrant-phase GEMM, asm-ds_read edition ----------------------
// BM=256, BN=NF*64, BK=64; 8 waves (2Mx4N). M/N-half tiles, double-buffered.
// 3 regions/K-tile: P0 (m0n0), P1 (m0n1), P23 (m1n1 + m1n0, barrier-free merge).
// Each region: {stage half(s) of t+1 | asm ds_read frags | lgkm0+SB | prio1
// MFMA prio0 | counted vmcnt | s_barrier}. Waits never 0 in the main loop.
// FINAL K-tile is PEELED with exact waits (vmcnt(2)/vmcnt(0)): with no t+1
// staging, the steady-state counted waits become no-ops and under-wait (the
// r5 race). Wait ALWAYS precedes barrier so all waves' writes are visible.
template <int NF, bool OUT_BF16, bool HAS_BIAS, bool HAS_RES, bool GELU, bool VTR>
__global__ __launch_bounds__(512, 2) void gemm6(
    const bf16* __restrict__ A, int lda, size_t sA,
    const bf16* __restrict__ BT, int ldb, size_t sB,
    void* Cv, size_t sC,
    const float* __restrict__ bias, const float* res, bf16* vtr,
    int N, int K, float alpha, int gx, int gy) {
  constexpr int BN = NF * 64;
  constexpr int NI = NF / 2;
  constexpr int BHALF = NF == 4 ? 16384 : 8192;
  constexpr int LB = NF == 4 ? 2 : 1;       // loads per B-half per thread
  constexpr int W_AB = 2 + LB;              // = LA + LB
  __shared__ __align__(16) char lds_storage[65536 + (NF == 4 ? 65536 : 32768)];
  const unsigned ldsAu = (unsigned)(uintptr_t)(c3*)lds_storage;
  const unsigned ldsBu = ldsAu + 65536;

  const int tid = threadIdx.x;
  const int lane = tid & 63;
  const int wave = tid >> 6;
  const int wm = wave >> 2, wn = wave & 3;
  const int lr = lane & 15, lq = lane >> 4;

  int id = blockIdx.x;
  const int nwg = gridDim.x;
  if ((nwg & 7) == 0) id = (id & 7) * (nwg >> 3) + (id >> 3);  // XCD swizzle
  const int bx = id % gx;
  const int rem = id / gx;
  const int by = rem % gy;
  const int bz = rem / gy;
  const int m0 = by * 256, n0 = bx * BN;

  // staging: thread -> (row = tid>>3, 16B chunk = tid&7); source column
  // pre-swizzled so linear GLL dest + XOR'd ds_read are consistent
  const int srow = tid >> 3;
  const int schunk = ((tid & 7) ^ (srow & 7)) * 8;
  const bf16* gA = A + sA * bz + (size_t)(m0 + srow) * lda + schunk;
  const bf16* gB = BT + sB * bz + (size_t)(n0 + srow) * ldb + schunk;

  const int nk = K >> 6;

  auto stA = [&](int tt, int h) {
    const bf16* s = gA + (size_t)(h * 128) * lda + (size_t)tt * 64;
    char* d = lds_storage + (((tt & 1) * 2 + h) << 14) + tid * 16;
    GLL(s, d);
    GLL(s + (size_t)64 * lda, d + 8192);
  };
  auto stB = [&](int tt, int h) {
    const bf16* s = gB + (size_t)(h * (BN / 2)) * ldb + (size_t)tt * 64;
    char* d = lds_storage + 65536 + ((tt & 1) * 2 + h) * BHALF + tid * 16;
    GLL(s, d);
    if constexpr (NF == 4) GLL(s + (size_t)64 * ldb, d + 8192);
  };

  // ds_read bases: row*128 + ((chunk ^ (row&7))<<4); kk=1 flips addr bit6 (^64)
  const unsigned aB0 = (wm * 64 + lr) * 128 + ((lq ^ (lr & 7)) << 4);
  const unsigned bRow = (NF == 4) ? (wn * 32 + lr) : (wn * 16 + lr);
  const unsigned bB0 = bRow * 128 + ((lq ^ (lr & 7)) << 4);

  floatx4 acc[2][2][4][NI] = {};

  // prologue: stage tile 0 in ledger order A0,B0,B1,A1
  stA(0, 0); stB(0, 0); stB(0, 1); stA(0, 1);
  vmwait<W_AB>();
  __builtin_amdgcn_s_barrier();

  for (int t = 0; t + 1 < nk; ++t) {
    const unsigned As0 = ldsAu + (((t & 1) * 2 + 0) << 14);
    const unsigned As1 = As0 + 16384;
    const unsigned Bs0 = ldsBu + ((t & 1) * 2 + 0) * BHALF;
    const unsigned Bs1 = Bs0 + BHALF;
    short8 a0[4], a1[4], b0[NI], b1[NI], c0[NI], c1[NI];

    // ===== P0: quadrant (m0,n0); stage A0(t+1)
    stA(t + 1, 0);
    {
      const unsigned aA = As0 + aB0, aX = aA ^ 64;
      a0[0] = dsr<0>(aA);  a0[1] = dsr<2048>(aA);  a0[2] = dsr<4096>(aA);  a0[3] = dsr<6144>(aA);
      a1[0] = dsr<0>(aX);  a1[1] = dsr<2048>(aX);  a1[2] = dsr<4096>(aX);  a1[3] = dsr<6144>(aX);
      const unsigned bA = Bs0 + bB0, bX = bA ^ 64;
      b0[0] = dsr<0>(bA); b1[0] = dsr<0>(bX);
      if constexpr (NI > 1) { b0[1] = dsr<2048>(bA); b1[1] = dsr<2048>(bX); }
    }
    lgkm0_fence();
    __builtin_amdgcn_s_setprio(1);
#pragma unroll
    for (int mi = 0; mi < 4; ++mi)
#pragma unroll
      for (int ni = 0; ni < NI; ++ni)
        acc[0][0][mi][ni] = __builtin_amdgcn_mfma_f32_16x16x32_bf16(a0[mi], b0[ni], acc[0][0][mi][ni], 0, 0, 0);
#pragma unroll
    for (int mi = 0; mi < 4; ++mi)
#pragma unroll
      for (int ni = 0; ni < NI; ++ni)
        acc[0][0][mi][ni] = __builtin_amdgcn_mfma_f32_16x16x32_bf16(a1[mi], b1[ni], acc[0][0][mi][ni], 0, 0, 0);
    __builtin_amdgcn_s_setprio(0);
    vmwait<4>();
    __builtin_amdgcn_s_barrier();

    // ===== P1: quadrant (m0,n1); stage B0(t+1); reuse a0/a1
    stB(t + 1, 0);
    {
      const unsigned bA = Bs1 + bB0, bX = bA ^ 64;
      b0[0] = dsr<0>(bA); b1[0] = dsr<0>(bX);
      if constexpr (NI > 1) { b0[1] = dsr<2048>(bA); b1[1] = dsr<2048>(bX); }
    }
    lgkm0_fence();
    __builtin_amdgcn_s_setprio(1);
#pragma unroll
    for (int mi = 0; mi < 4; ++mi)
#pragma unroll
      for (int ni = 0; ni < NI; ++ni)
        acc[0][1][mi][ni] = __builtin_amdgcn_mfma_f32_16x16x32_bf16(a0[mi], b0[ni], acc[0][1][mi][ni], 0, 0, 0);
#pragma unroll
    for (int mi = 0; mi < 4; ++mi)
#pragma unroll
      for (int ni = 0; ni < NI; ++ni)
        acc[0][1][mi][ni] = __builtin_amdgcn_mfma_f32_16x16x32_bf16(a1[mi], b1[ni], acc[0][1][mi][ni], 0, 0, 0);
    __builtin_amdgcn_s_setprio(0);
    vmwait<W_AB>();
    __builtin_amdgcn_s_barrier();

    // ===== P23: quadrants (m1,n1) then (m1,n0); stage B1(t+1), A1(t+1)
    stB(t + 1, 1);
    {
      const unsigned aA = As1 + aB0, aX = aA ^ 64;
      a0[0] = dsr<0>(aA);  a0[1] = dsr<2048>(aA);  a0[2] = dsr<4096>(aA);  a0[3] = dsr<6144>(aA);
      a1[0] = dsr<0>(aX);  a1[1] = dsr<2048>(aX);  a1[2] = dsr<4096>(aX);  a1[3] = dsr<6144>(aX);
    }
    lgkm0_fence();
    __builtin_amdgcn_s_setprio(1);
#pragma unroll
    for (int mi = 0; mi < 4; ++mi)
#pragma unroll
      for (int ni = 0; ni < NI; ++ni)
        acc[1][1][mi][ni] = __builtin_amdgcn_mfma_f32_16x16x32_bf16(a0[mi], b0[ni], acc[1][1][mi][ni], 0, 0, 0);
#pragma unroll
    for (int mi = 0; mi < 4; ++mi)
#pragma unroll
      for (int ni = 0; ni < NI; ++ni)
        acc[1][1][mi][ni] = __builtin_amdgcn_mfma_f32_16x16x32_bf16(a1[mi], b1[ni], acc[1][1][mi][ni], 0, 0, 0);
    __builtin_amdgcn_s_setprio(0);
    stA(t + 1, 1);
    {
      const unsigned bA = Bs0 + bB0, bX = bA ^ 64;
      c0[0] = dsr<0>(bA); c1[0] = dsr<0>(bX);
      if constexpr (NI > 1) { c0[1] = dsr<2048>(bA); c1[1] = dsr<2048>(bX); }
    }
    lgkm0_fence();
    __builtin_amdgcn_s_setprio(1);
#pragma unroll
    for (int mi = 0; mi < 4; ++mi)
#pragma unroll
      for (int ni = 0; ni < NI; ++ni)
        acc[1][0][mi][ni] = __builtin_amdgcn_mfma_f32_16x16x32_bf16(a0[mi], c0[ni], acc[1][0][mi][ni], 0, 0, 0);
#pragma unroll
    for (int mi = 0; mi < 4; ++mi)
#pragma unroll
      for (int ni = 0; ni < NI; ++ni)
        acc[1][0][mi][ni] = __builtin_amdgcn_mfma_f32_16x16x32_bf16(a1[mi], c1[ni], acc[1][0][mi][ni], 0, 0, 0);
    __builtin_amdgcn_s_setprio(0);
    vmwait<W_AB>();
    __builtin_amdgcn_s_barrier();
  }

  {  // ===== peeled final K-tile (t = nk-1): no staging, exact waits
    const int t = nk - 1;
    const unsigned As0 = ldsAu + (((t & 1) * 2 + 0) << 14);
    const unsigned As1 = As0 + 16384;
    const unsigned Bs0 = ldsBu + ((t & 1) * 2 + 0) * BHALF;
    const unsigned Bs1 = Bs0 + BHALF;
    short8 a0[4], a1[4], b0[NI], b1[NI], c0[NI], c1[NI];

    // P0: (m0,n0) — As0/Bs0 already retired by the loop's last wait+barrier
    {
      const unsigned aA = As0 + aB0, aX = aA ^ 64;
      a0[0] = dsr<0>(aA);  a0[1] = dsr<2048>(aA);  a0[2] = dsr<4096>(aA);  a0[3] = dsr<6144>(aA);
      a1[0] = dsr<0>(aX);  a1[1] = dsr<2048>(aX);  a1[2] = dsr<4096>(aX);  a1[3] = dsr<6144>(aX);
      const unsigned bA = Bs0 + bB0, bX = bA ^ 64;
      b0[0] = dsr<0>(bA); b1[0] = dsr<0>(bX);
      if constexpr (NI > 1) { b0[1] = dsr<2048>(bA); b1[1] = dsr<2048>(bX); }
    }
    lgkm0_fence();
#pragma unroll
    for (int mi = 0; mi < 4; ++mi)
#pragma unroll
      for (int ni = 0; ni < NI; ++ni)
        acc[0][0][mi][ni] = __builtin_amdgcn_mfma_f32_16x16x32_bf16(a0[mi], b0[ni], acc[0][0][mi][ni], 0, 0, 0);
#pragma unroll
    for (int mi = 0; mi < 4; ++mi)
#pragma unroll
      for (int ni = 0; ni < NI; ++ni)
        acc[0][0][mi][ni] = __builtin_amdgcn_mfma_f32_16x16x32_bf16(a1[mi], b1[ni], acc[0][0][mi][ni], 0, 0, 0);
    vmwait<2>();  // retire B1(nk-1) (all waves, + barrier below)
    __builtin_amdgcn_s_barrier();

    // P1: (m0,n1)
    {
      const unsigned bA = Bs1 + bB0, bX = bA ^ 64;
      b0[0] = dsr<0>(bA); b1[0] = dsr<0>(bX);
      if constexpr (NI > 1) { b0[1] = dsr<2048>(bA); b1[1] = dsr<2048>(bX); }
    }
    lgkm0_fence();
#pragma unroll
    for (int mi = 0; mi < 4; ++mi)
#pragma unroll
      for (int ni = 0; ni < NI; ++ni)
        acc[0][1][mi][ni] = __builtin_amdgcn_mfma_f32_16x16x32_bf16(a0[mi], b0[ni], acc[0][1][mi][ni], 0, 0, 0);
#pragma unroll
    for (int mi = 0; mi < 4; ++mi)
#pragma unroll
      for (int ni = 0; ni < NI; ++ni)
        acc[0][1][mi][ni] = __builtin_amdgcn_mfma_f32_16x16x32_bf16(a1[mi], b1[ni], acc[0][1][mi][ni], 0, 0, 0);
    vmwait<0>();  // retire A1(nk-1)
    __builtin_amdgcn_s_barrier();

    // P23: (m1,n1) then (m1,n0)
    {
      const unsigned aA = As1 + aB0, aX = aA ^ 64;
      a0[0] = dsr<0>(aA);  a0[1] = dsr<2048>(aA);  a0[2] = dsr<4096>(aA);  a0[3] = dsr<6144>(aA);
      a1[0] = dsr<0>(aX);  a1[1] = dsr<2048>(aX);  a1[2] = dsr<4096>(aX);  a1[3] = dsr<6144>(aX);
    }
    lgkm0_fence();
#pragma unroll
    for (int mi = 0; mi < 4; ++mi)
#pragma unroll
      for (int ni = 0; ni < NI; ++ni)
        acc[1][1][mi][ni] = __builtin_amdgcn_mfma_f32_16x16x32_bf16(a0[mi], b0[ni], acc[1][1][mi][ni], 0, 0, 0);
#pragma unroll
    for (int mi = 0; mi < 4; ++mi)
#pragma unroll
      for (int ni = 0; ni < NI; ++ni)
        acc[1][1][mi][ni] = __builtin_amdgcn_mfma_f32_16x16x32_bf16(a1[mi], b1[ni], acc[1][1][mi][ni], 0, 0, 0);
    {
      const unsigned bA = Bs0 + bB0, bX = bA ^ 64;
      c0[0] = dsr<0>(bA); c1[0] = dsr<0>(bX);
      if constexpr (NI > 1) { c0[1] = dsr<2048>(bA); c1[1] = dsr<2048>(bX); }
    }
    lgkm0_fence();
#pragma unroll
    for (int mi = 0; mi < 4; ++mi)
#pragma unroll
      for (int ni = 0; ni < NI; ++ni)
        acc[1][0][mi][ni] = __builtin_amdgcn_mfma_f32_16x16x32_bf16(a0[mi], c0[ni], acc[1][0][mi][ni], 0, 0, 0);
#pragma unroll
    for (int mi = 0; mi < 4; ++mi)
#pragma unroll
      for (int ni = 0; ni < NI; ++ni)
        acc[1][0][mi][ni] = __builtin_amdgcn_mfma_f32_16x16x32_bf16(a1[mi], c1[ni], acc[1][0][mi][ni], 0, 0, 0);
  }

  // epilogue: C/D frag map col=lane&15, row=(lane>>4)*4+r [m89-verified]
  float* Cf = (float*)Cv;
  bf16* Cb = (bf16*)Cv;
  const size_t cb = sC * bz;
#pragma unroll
  for (int mq = 0; mq < 2; ++mq)
#pragma unroll
    for (int nq = 0; nq < 2; ++nq)
#pragma unroll
      for (int mi = 0; mi < 4; ++mi) {
        const int row = m0 + mq * 128 + wm * 64 + mi * 16 + lq * 4;
#pragma unroll
        for (int ni = 0; ni < NI; ++ni) {
          const int col = n0 + nq * (BN / 2) + wn * (BN / 8) + ni * 16 + lr;
          const float bb = HAS_BIAS ? bias[col] : 0.f;
#pragma unroll
          for (int r = 0; r < 4; ++r) {
            float val = acc[mq][nq][mi][ni][r] * alpha + bb;
            if (GELU) val = 0.5f * val * (1.f + erff(val * 0.70710678118654752f));
            if (HAS_RES) val += res[(size_t)(row + r) * N + col];
            const size_t idx = cb + (size_t)(row + r) * N + col;
            if (OUT_BF16) Cb[idx] = __float2bfloat16(val);
            else Cf[idx] = val;
            if (VTR) {
              if (col >= 2048) {  // V columns: also write V^T [b][col-2048][row%S]
                const int rr = row + r;
                vtr[(((size_t)(rr >> 11) << 10) + (col - 2048)) * 2048 + (rr & 2047)] =
                    __float2bfloat16(val);
              }
            }
          }
        }
      }
}

extern "C" void kernel_launch(void* const* d_in, const int* in_sizes, int n_in,
                              void* d_out, int out_size, void* d_ws, size_t ws_size,
                              hipStream_t stream) {
  const int B = 4, S = 2048, D = 1024, DFF = 4096;
  const int M = B * S;
  const float* x   = (const float*)d_in[0];
  const float* wq  = (const float*)d_in[1];
  const float* bq  = (const float*)d_in[2];
  const float* wk  = (const float*)d_in[3];
  const float* bk  = (const float*)d_in[4];
  const float* wv  = (const float*)d_in[5];
  const float* bv  = (const float*)d_in[6];
  const float* wo  = (const float*)d_in[7];
  const float* bo  = (const float*)d_in[8];
  const float* w1  = (const float*)d_in[9];
  const float* b1  = (const float*)d_in[10];
  const float* w2  = (const float*)d_in[11];
  const float* b2  = (const float*)d_in[12];
  const float* g1  = (const float*)d_in[13];
  const float* be1 = (const float*)d_in[14];
  const float* g2  = (const float*)d_in[15];
  const float* be2 = (const float*)d_in[16];
  float* out = (float*)d_out;

  // workspace arena:
  //  0-6 wqkvT  6-8 woT  8-16 w1T  16-24 w2T  24 bqkv  25-41 h (bf16 MxD)
  //  41-89 qkv (bf16 Mx3072) / later hidden (bf16 MxDFF, 41-105)
  //  89-105 vT [4][D][S] bf16 (written by QKV epilogue)
  //  105+  scores fp32, chunk*16MB
  char* wsb = (char*)d_ws;
  const size_t MB1 = 1ull << 20;
  bf16* wqkvT = (bf16*)(wsb + 0 * MB1);
  bf16* woT   = (bf16*)(wsb + 6 * MB1);
  bf16* w1T   = (bf16*)(wsb + 8 * MB1);
  bf16* w2T   = (bf16*)(wsb + 16 * MB1);
  float* bqkv = (float*)(wsb + 24 * MB1);
  bf16* h     = (bf16*)(wsb + 25 * MB1);
  bf16* qkv   = (bf16*)(wsb + 41 * MB1);
  bf16* hidden = (bf16*)(wsb + 41 * MB1);
  bf16* vTall = (bf16*)(wsb + 89 * MB1);
  float* sc   = (float*)(wsb + 105 * MB1);

  int chunk = 1;
  if (ws_size > 105 * MB1) {
    size_t c = (ws_size - 105 * MB1) / (16 * MB1);
    chunk = (int)(c > 4 ? 4 : (c < 1 ? 1 : c));
  }

  dim3 tb(32, 8);
  wtrans_kernel<<<dim3(32, 32), tb, 0, stream>>>(wq, wqkvT, D, D);
  wtrans_kernel<<<dim3(32, 32), tb, 0, stream>>>(wk, wqkvT + (size_t)1024 * 1024, D, D);
  wtrans_kernel<<<dim3(32, 32), tb, 0, stream>>>(wv, wqkvT + (size_t)2048 * 1024, D, D);
  wtrans_kernel<<<dim3(32, 32), tb, 0, stream>>>(wo, woT, D, D);
  wtrans_kernel<<<dim3(128, 32), tb, 0, stream>>>(w1, w1T, D, DFF);
  wtrans_kernel<<<dim3(32, 128), tb, 0, stream>>>(w2, w2T, DFF, D);
  hipMemcpyAsync(bqkv, bq, 4096, hipMemcpyDeviceToDevice, stream);
  hipMemcpyAsync(bqkv + 1024, bk, 4096, hipMemcpyDeviceToDevice, stream);
  hipMemcpyAsync(bqkv + 2048, bv, 4096, hipMemcpyDeviceToDevice, stream);

  // h = LN1(x)
  ln_kernel<<<M, 256, 0, stream>>>(x, g1, be1, h);

  // qkv = h @ [wq|wk|wv] + biases; V columns also emitted transposed into vTall
  gemm6<2, true, true, false, false, true><<<24 * 32, 512, 0, stream>>>(
      h, D, 0, wqkvT, D, 0, qkv, 0, bqkv, nullptr, vTall, 3072, D, 1.f, 24, 32);

  for (int b0 = 0; b0 < B; b0 += chunk) {
    int c = (B - b0 < chunk) ? (B - b0) : chunk;
    // scores = q @ k^T * 0.125 (fp32)
    gemm6<4, false, false, false, false, false><<<64 * c, 512, 0, stream>>>(
        qkv + (size_t)b0 * S * 3072, 3072, (size_t)S * 3072,
        qkv + (size_t)b0 * S * 3072 + 1024, 3072, (size_t)S * 3072,
        sc, (size_t)S * S, nullptr, nullptr, nullptr, S, D, 0.125f, 8, 8);
    softmax_kernel<<<c * S, 256, 0, stream>>>(sc);
    // ctx = probs @ vT^T (probs bf16 in-place over fp32 rows, pitch 2S)
    gemm6<2, true, false, false, false, false><<<64 * c, 512, 0, stream>>>(
        (const bf16*)sc, 2 * S, (size_t)S * 2 * S,
        vTall + (size_t)b0 * D * S, S, (size_t)D * S,
        h + (size_t)b0 * S * D, (size_t)S * D, nullptr, nullptr, nullptr, D, S, 1.f, 8, 8);
  }

  // x2 = ctx @ wo + bo + x -> d_out (fp32)
  gemm6<2, false, true, true, false, false><<<8 * 32, 512, 0, stream>>>(
      h, D, 0, woT, D, 0, out, 0, bo, x, nullptr, D, D, 1.f, 8, 32);

  // h = LN2(x2)
  ln_kernel<<<M, 256, 0, stream>>>(out, g2, be2, h);

  // hidden = gelu(h @ w1 + b1)
  gemm6<4, true, true, false, true, false><<<16 * 32, 512, 0, stream>>>(
      h, D, 0, w1T, D, 0, hidden, 0, b1, nullptr, nullptr, DFF, D, 1.f, 16, 32);

  // out = hidden @ w2 + b2 + x2 (in-place residual)
  gemm6<2, false, true, true, false, false><<<8 * 32, 512, 0, stream>>>(
      hidden, DFF, 0, w2T, DFF, 0, out, 0, b2, out, nullptr, D, DFF, 1.f, 8, 32);
}

// Round 7
// 459.170 us; speedup vs baseline: 1.4772x; 1.0110x over previous
//
#include <hip/hip_runtime.h>
#include <hip/hip_bf16.h>

typedef __hip_bfloat16 bf16;
typedef __attribute__((ext_vector_type(8))) short short8;
typedef __attribute__((ext_vector_type(4))) float floatx4;
typedef __attribute__((address_space(3))) char c3;

template <int V> struct ic { static constexpr int value = V; };

__device__ __forceinline__ unsigned short f2bf(float x) {
  unsigned u = __builtin_bit_cast(unsigned, x);
  unsigned r = (u + 0x7fffu + ((u >> 16) & 1u)) >> 16;
  return (unsigned short)r;
}

#define GLL(g, l) __builtin_amdgcn_global_load_lds(                                  \
    (const __attribute__((address_space(1))) void*)(g),                              \
    (__attribute__((address_space(3))) void*)(l), 16, 0, 0)

template <int N> __device__ __forceinline__ void vmwait() {
  asm volatile("s_waitcnt vmcnt(%0)" ::"i"(N) : "memory");
}
template <int OFF> __device__ __forceinline__ short8 dsr(unsigned a) {
  short8 r;
  asm volatile("ds_read_b128 %0, %1 offset:%2" : "=v"(r) : "v"(a), "i"(OFF));
  return r;
}
__device__ __forceinline__ void lgkm0_fence() {
  asm volatile("s_waitcnt lgkmcnt(0)" ::: "memory");
  __builtin_amdgcn_sched_barrier(0);
}

// ---------------- weight transpose+convert: fp32 [K][N] -> bf16 [N][K] ----------
__global__ __launch_bounds__(256) void wtrans_kernel(const float* __restrict__ in,
                                                     bf16* __restrict__ out,
                                                     int K, int N) {
  __shared__ float tile[32][33];
  int tx = threadIdx.x, ty = threadIdx.y;
  int n0 = blockIdx.x * 32, k0 = blockIdx.y * 32;
#pragma unroll
  for (int i = 0; i < 32; i += 8)
    tile[ty + i][tx] = in[(size_t)(k0 + ty + i) * N + (n0 + tx)];
  __syncthreads();
#pragma unroll
  for (int i = 0; i < 32; i += 8)
    out[(size_t)(n0 + ty + i) * K + (k0 + tx)] = __float2bfloat16(tile[tx][ty + i]);
}

// ---------------- LayerNorm fp32 -> bf16, D=1024, one block(256)/row ------------
__global__ __launch_bounds__(256) void ln_kernel(const float* __restrict__ x,
                                                 const float* __restrict__ g,
                                                 const float* __restrict__ b,
                                                 bf16* __restrict__ out) {
  const int D = 1024;
  size_t row = blockIdx.x;
  int t = threadIdx.x;
  float4 v = ((const float4*)(x + row * D))[t];
  float s  = v.x + v.y + v.z + v.w;
  float ss = v.x * v.x + v.y * v.y + v.z * v.z + v.w * v.w;
#pragma unroll
  for (int off = 32; off > 0; off >>= 1) {
    s  += __shfl_xor(s, off);
    ss += __shfl_xor(ss, off);
  }
  __shared__ float rs[4], rss[4];
  int wv = t >> 6;
  if ((t & 63) == 0) { rs[wv] = s; rss[wv] = ss; }
  __syncthreads();
  s  = rs[0] + rs[1] + rs[2] + rs[3];
  ss = rss[0] + rss[1] + rss[2] + rss[3];
  float mu  = s * (1.f / D);
  float inv = rsqrtf(ss * (1.f / D) - mu * mu + 1e-5f);
  float4 gv = ((const float4*)g)[t];
  float4 bv = ((const float4*)b)[t];
  ushort4 o;
  o.x = f2bf((v.x - mu) * inv * gv.x + bv.x);
  o.y = f2bf((v.y - mu) * inv * gv.y + bv.y);
  o.z = f2bf((v.z - mu) * inv * gv.z + bv.z);
  o.w = f2bf((v.w - mu) * inv * gv.w + bv.w);
  ((ushort4*)(out + row * D))[t] = o;
}

// ---------------- softmax: fp32 row (2048) -> bf16 written in place -------------
__global__ __launch_bounds__(256) void softmax_kernel(float* sc) {
  const int S = 2048;
  float* p = sc + (size_t)blockIdx.x * S;
  int t = threadIdx.x;
  float4 v0 = ((const float4*)p)[2 * t];
  float4 v1 = ((const float4*)p)[2 * t + 1];
  float f[8] = {v0.x, v0.y, v0.z, v0.w, v1.x, v1.y, v1.z, v1.w};
  float m = f[0];
#pragma unroll
  for (int j = 1; j < 8; ++j) m = fmaxf(m, f[j]);
#pragma unroll
  for (int off = 32; off > 0; off >>= 1) m = fmaxf(m, __shfl_xor(m, off));
  __shared__ float r1[4], r2[4];
  int wv = t >> 6;
  if ((t & 63) == 0) r1[wv] = m;
  __syncthreads();
  m = fmaxf(fmaxf(r1[0], r1[1]), fmaxf(r1[2], r1[3]));
  float s = 0.f;
#pragma unroll
  for (int j = 0; j < 8; ++j) { f[j] = __expf(f[j] - m); s += f[j]; }
#pragma unroll
  for (int off = 32; off > 0; off >>= 1) s += __shfl_xor(s, off);
  if ((t & 63) == 0) r2[wv] = s;
  __syncthreads();
  s = r2[0] + r2[1] + r2[2] + r2[3];
  float inv = 1.f / s;
  unsigned u0 = f2bf(f[0] * inv), u1 = f2bf(f[1] * inv);
  unsigned u2 = f2bf(f[2] * inv), u3 = f2bf(f[3] * inv);
  unsigned u4 = f2bf(f[4] * inv), u5 = f2bf(f[5] * inv);
  unsigned u6 = f2bf(f[6] * inv), u7 = f2bf(f[7] * inv);
  uint4 o;
  o.x = u0 | (u1 << 16);
  o.y = u2 | (u3 << 16);
  o.z = u4 | (u5 << 16);
  o.w = u6 | (u7 << 16);
  ((uint4*)p)[t] = o;
}

// ---------------- deep-prefetch quadrant GEMM --------------------------------
// BM=256, BN=NF*64, BK=64; 8 waves (2Mx4N). Regions per K-tile: P0 (m0n0, reads
// As0+Bs0, Bs0 frags KEPT in regs), P1 (m0n1, reads Bs1), P23 (m1n1 + m1n0,
// reads As1; Bs0 quadrant uses kept regs). Each half-slot is re-staged with
// tile t+2 data right AFTER its last reader's barrier (per-half rotation on a
// double buffer): P0 stages A1(t+1); P1 stages A0(t+2),B0(t+2); P23 stages
// B1(t+2) -> ~4-region (~1000cy) prefetch lead >= HBM latency.
// FIFO ledger (LA=2, LB=NF/2; waits hold before each barrier):
//  steady: endP0 retire B1(t)   -> NF4 vmcnt(10) / NF2 (8)
//          endP1 retire A1(t)   -> NF4 (12) / NF2 (9)
//          endP23 retire B0(t+1)-> NF4 (10) / NF2 (7)
//  t=nk-2: (10|8), (8|6), (4|3);  t=nk-1: (2|2), (0), skip.
template <int NF, bool OUT_BF16, bool HAS_BIAS, bool HAS_RES, bool GELU, bool VTR>
__global__ __launch_bounds__(512, 2) void gemm7(
    const bf16* __restrict__ A, int lda, size_t sA,
    const bf16* __restrict__ BT, int ldb, size_t sB,
    void* Cv, size_t sC,
    const float* __restrict__ bias, const float* res, bf16* vtr,
    int N, int K, float alpha, int gx, int gy) {
  constexpr int BN = NF * 64;
  constexpr int NI = NF / 2;
  constexpr int BHALF = NF == 4 ? 16384 : 8192;
  __shared__ __align__(16) char lds_storage[65536 + (NF == 4 ? 65536 : 32768)];
  const unsigned ldsAu = (unsigned)(uintptr_t)(c3*)lds_storage;
  const unsigned ldsBu = ldsAu + 65536;

  const int tid = threadIdx.x;
  const int lane = tid & 63;
  const int wave = tid >> 6;
  const int wm = wave >> 2, wn = wave & 3;
  const int lr = lane & 15, lq = lane >> 4;

  int id = blockIdx.x;
  const int nwg = gridDim.x;
  if ((nwg & 7) == 0) id = (id & 7) * (nwg >> 3) + (id >> 3);  // XCD swizzle
  const int bx = id % gx;
  const int rem = id / gx;
  const int by = rem % gy;
  const int bz = rem / gy;
  const int m0 = by * 256, n0 = bx * BN;

  // staging: thread -> (row = tid>>3, 16B chunk = tid&7); source column
  // pre-swizzled so linear GLL dest + XOR'd ds_read are consistent
  const int srow = tid >> 3;
  const int schunk = ((tid & 7) ^ (srow & 7)) * 8;
  const bf16* gA = A + sA * bz + (size_t)(m0 + srow) * lda + schunk;
  const bf16* gB = BT + sB * bz + (size_t)(n0 + srow) * ldb + schunk;

  const int nk = K >> 6;

  auto stA = [&](int tt, int h) {
    const bf16* s = gA + (size_t)(h * 128) * lda + (size_t)tt * 64;
    char* d = lds_storage + (((tt & 1) * 2 + h) << 14) + tid * 16;
    GLL(s, d);
    GLL(s + (size_t)64 * lda, d + 8192);
  };
  auto stB = [&](int tt, int h) {
    const bf16* s = gB + (size_t)(h * (BN / 2)) * ldb + (size_t)tt * 64;
    char* d = lds_storage + 65536 + ((tt & 1) * 2 + h) * BHALF + tid * 16;
    GLL(s, d);
    if constexpr (NF == 4) GLL(s + (size_t)64 * ldb, d + 8192);
  };

  // ds_read bases: row*128 + ((chunk ^ (row&7))<<4); kk=1 flips addr bit6 (^64)
  const unsigned aB0 = (wm * 64 + lr) * 128 + ((lq ^ (lr & 7)) << 4);
  const unsigned bRow = (NF == 4) ? (wn * 32 + lr) : (wn * 16 + lr);
  const unsigned bB0 = bRow * 128 + ((lq ^ (lr & 7)) << 4);

  floatx4 acc[2][2][4][NI] = {};

  // prologue (ledger order): A0(0),B0(0),B1(0),A1(0),A0(1),B0(1),B1(1)
  stA(0, 0); stB(0, 0); stB(0, 1); stA(0, 1);
  stA(1, 0); stB(1, 0); stB(1, 1);
  vmwait<NF == 4 ? 10 : 7>();  // retire A0(0),B0(0)
  __builtin_amdgcn_s_barrier();

  auto tile_body = [&](int t, auto modeC) {
    constexpr int MODE = decltype(modeC)::value;  // 0 steady, 1 nk-2, 2 nk-1
    constexpr int W0  = MODE < 2 ? (NF == 4 ? 10 : 8) : 2;
    constexpr int W1  = MODE == 0 ? (NF == 4 ? 12 : 9)
                                  : (MODE == 1 ? (NF == 4 ? 8 : 6) : 0);
    constexpr int W23 = MODE == 0 ? (NF == 4 ? 10 : 7)
                                  : (MODE == 1 ? (NF == 4 ? 4 : 3) : -1);
    const unsigned As0 = ldsAu + (((t & 1) * 2 + 0) << 14);
    const unsigned As1 = As0 + 16384;
    const unsigned Bs0 = ldsBu + ((t & 1) * 2 + 0) * BHALF;
    const unsigned Bs1 = Bs0 + BHALF;
    short8 a0[4], a1[4], b0[NI], b1[NI], bb0[NI], bb1[NI];

    // ===== P0: (m0,n0); keep Bs0 frags (bb); stage A1(t+1)
    {
      const unsigned aA = As0 + aB0, aX = aA ^ 64;
      a0[0] = dsr<0>(aA);  a0[1] = dsr<2048>(aA);  a0[2] = dsr<4096>(aA);  a0[3] = dsr<6144>(aA);
      a1[0] = dsr<0>(aX);  a1[1] = dsr<2048>(aX);  a1[2] = dsr<4096>(aX);  a1[3] = dsr<6144>(aX);
      const unsigned bA = Bs0 + bB0, bX = bA ^ 64;
      bb0[0] = dsr<0>(bA); bb1[0] = dsr<0>(bX);
      if constexpr (NI > 1) { bb0[1] = dsr<2048>(bA); bb1[1] = dsr<2048>(bX); }
    }
    if constexpr (MODE < 2) stA(t + 1, 1);
    lgkm0_fence();
    __builtin_amdgcn_s_setprio(1);
#pragma unroll
    for (int mi = 0; mi < 4; ++mi)
#pragma unroll
      for (int ni = 0; ni < NI; ++ni)
        acc[0][0][mi][ni] = __builtin_amdgcn_mfma_f32_16x16x32_bf16(a0[mi], bb0[ni], acc[0][0][mi][ni], 0, 0, 0);
#pragma unroll
    for (int mi = 0; mi < 4; ++mi)
#pragma unroll
      for (int ni = 0; ni < NI; ++ni)
        acc[0][0][mi][ni] = __builtin_amdgcn_mfma_f32_16x16x32_bf16(a1[mi], bb1[ni], acc[0][0][mi][ni], 0, 0, 0);
    __builtin_amdgcn_s_setprio(0);
    vmwait<W0>();
    __builtin_amdgcn_s_barrier();

    // ===== P1: (m0,n1); reads Bs1; stage A0(t+2), B0(t+2)
    {
      const unsigned bA = Bs1 + bB0, bX = bA ^ 64;
      b0[0] = dsr<0>(bA); b1[0] = dsr<0>(bX);
      if constexpr (NI > 1) { b0[1] = dsr<2048>(bA); b1[1] = dsr<2048>(bX); }
    }
    if constexpr (MODE == 0) { stA(t + 2, 0); stB(t + 2, 0); }
    lgkm0_fence();
    __builtin_amdgcn_s_setprio(1);
#pragma unroll
    for (int mi = 0; mi < 4; ++mi)
#pragma unroll
      for (int ni = 0; ni < NI; ++ni)
        acc[0][1][mi][ni] = __builtin_amdgcn_mfma_f32_16x16x32_bf16(a0[mi], b0[ni], acc[0][1][mi][ni], 0, 0, 0);
#pragma unroll
    for (int mi = 0; mi < 4; ++mi)
#pragma unroll
      for (int ni = 0; ni < NI; ++ni)
        acc[0][1][mi][ni] = __builtin_amdgcn_mfma_f32_16x16x32_bf16(a1[mi], b1[ni], acc[0][1][mi][ni], 0, 0, 0);
    __builtin_amdgcn_s_setprio(0);
    vmwait<W1>();
    __builtin_amdgcn_s_barrier();

    // ===== P23: (m1,n1) with b (Bs1 regs), then (m1,n0) with bb (kept Bs0 regs);
    //            reads As1; stage B1(t+2)
    {
      const unsigned aA = As1 + aB0, aX = aA ^ 64;
      a0[0] = dsr<0>(aA);  a0[1] = dsr<2048>(aA);  a0[2] = dsr<4096>(aA);  a0[3] = dsr<6144>(aA);
      a1[0] = dsr<0>(aX);  a1[1] = dsr<2048>(aX);  a1[2] = dsr<4096>(aX);  a1[3] = dsr<6144>(aX);
    }
    if constexpr (MODE == 0) stB(t + 2, 1);
    lgkm0_fence();
    __builtin_amdgcn_s_setprio(1);
#pragma unroll
    for (int mi = 0; mi < 4; ++mi)
#pragma unroll
      for (int ni = 0; ni < NI; ++ni)
        acc[1][1][mi][ni] = __builtin_amdgcn_mfma_f32_16x16x32_bf16(a0[mi], b0[ni], acc[1][1][mi][ni], 0, 0, 0);
#pragma unroll
    for (int mi = 0; mi < 4; ++mi)
#pragma unroll
      for (int ni = 0; ni < NI; ++ni)
        acc[1][1][mi][ni] = __builtin_amdgcn_mfma_f32_16x16x32_bf16(a1[mi], b1[ni], acc[1][1][mi][ni], 0, 0, 0);
#pragma unroll
    for (int mi = 0; mi < 4; ++mi)
#pragma unroll
      for (int ni = 0; ni < NI; ++ni)
        acc[1][0][mi][ni] = __builtin_amdgcn_mfma_f32_16x16x32_bf16(a0[mi], bb0[ni], acc[1][0][mi][ni], 0, 0, 0);
#pragma unroll
    for (int mi = 0; mi < 4; ++mi)
#pragma unroll
      for (int ni = 0; ni < NI; ++ni)
        acc[1][0][mi][ni] = __builtin_amdgcn_mfma_f32_16x16x32_bf16(a1[mi], bb1[ni], acc[1][0][mi][ni], 0, 0, 0);
    __builtin_amdgcn_s_setprio(0);
    if constexpr (W23 >= 0) {
      vmwait<W23>();
      __builtin_amdgcn_s_barrier();
    }
  };

  for (int t = 0; t + 2 < nk; ++t) tile_body(t, ic<0>{});
  tile_body(nk - 2, ic<1>{});
  tile_body(nk - 1, ic<2>{});

  // epilogue: C/D frag map col=lane&15, row=(lane>>4)*4+r [m89-verified]
  float* Cf = (float*)Cv;
  bf16* Cb = (bf16*)Cv;
  const size_t cb = sC * bz;
#pragma unroll
  for (int mq = 0; mq < 2; ++mq)
#pragma unroll
    for (int nq = 0; nq < 2; ++nq)
#pragma unroll
      for (int mi = 0; mi < 4; ++mi) {
        const int row = m0 + mq * 128 + wm * 64 + mi * 16 + lq * 4;
#pragma unroll
        for (int ni = 0; ni < NI; ++ni) {
          const int col = n0 + nq * (BN / 2) + wn * (BN / 8) + ni * 16 + lr;
          const float bb = HAS_BIAS ? bias[col] : 0.f;
#pragma unroll
          for (int r = 0; r < 4; ++r) {
            float val = acc[mq][nq][mi][ni][r] * alpha + bb;
            if (GELU) val = 0.5f * val * (1.f + erff(val * 0.70710678118654752f));
            if (HAS_RES) val += res[(size_t)(row + r) * N + col];
            const size_t idx = cb + (size_t)(row + r) * N + col;
            if (OUT_BF16) Cb[idx] = __float2bfloat16(val);
            else Cf[idx] = val;
            if (VTR) {
              if (col >= 2048) {  // V columns: also write V^T [b][col-2048][row%S]
                const int rr = row + r;
                vtr[(((size_t)(rr >> 11) << 10) + (col - 2048)) * 2048 + (rr & 2047)] =
                    __float2bfloat16(val);
              }
            }
          }
        }
      }
}

extern "C" void kernel_launch(void* const* d_in, const int* in_sizes, int n_in,
                              void* d_out, int out_size, void* d_ws, size_t ws_size,
                              hipStream_t stream) {
  const int B = 4, S = 2048, D = 1024, DFF = 4096;
  const int M = B * S;
  const float* x   = (const float*)d_in[0];
  const float* wq  = (const float*)d_in[1];
  const float* bq  = (const float*)d_in[2];
  const float* wk  = (const float*)d_in[3];
  const float* bk  = (const float*)d_in[4];
  const float* wv  = (const float*)d_in[5];
  const float* bv  = (const float*)d_in[6];
  const float* wo  = (const float*)d_in[7];
  const float* bo  = (const float*)d_in[8];
  const float* w1  = (const float*)d_in[9];
  const float* b1  = (const float*)d_in[10];
  const float* w2  = (const float*)d_in[11];
  const float* b2  = (const float*)d_in[12];
  const float* g1  = (const float*)d_in[13];
  const float* be1 = (const float*)d_in[14];
  const float* g2  = (const float*)d_in[15];
  const float* be2 = (const float*)d_in[16];
  float* out = (float*)d_out;

  // workspace arena:
  //  0-6 wqkvT  6-8 woT  8-16 w1T  16-24 w2T  24 bqkv  25-41 h (bf16 MxD)
  //  41-89 qkv (bf16 Mx3072) / later hidden (bf16 MxDFF, 41-105)
  //  89-105 vT [4][D][S] bf16 (written by QKV epilogue)
  //  105+  scores fp32, chunk*16MB
  char* wsb = (char*)d_ws;
  const size_t MB1 = 1ull << 20;
  bf16* wqkvT = (bf16*)(wsb + 0 * MB1);
  bf16* woT   = (bf16*)(wsb + 6 * MB1);
  bf16* w1T   = (bf16*)(wsb + 8 * MB1);
  bf16* w2T   = (bf16*)(wsb + 16 * MB1);
  float* bqkv = (float*)(wsb + 24 * MB1);
  bf16* h     = (bf16*)(wsb + 25 * MB1);
  bf16* qkv   = (bf16*)(wsb + 41 * MB1);
  bf16* hidden = (bf16*)(wsb + 41 * MB1);
  bf16* vTall = (bf16*)(wsb + 89 * MB1);
  float* sc   = (float*)(wsb + 105 * MB1);

  int chunk = 1;
  if (ws_size > 105 * MB1) {
    size_t c = (ws_size - 105 * MB1) / (16 * MB1);
    chunk = (int)(c > 4 ? 4 : (c < 1 ? 1 : c));
  }

  dim3 tb(32, 8);
  wtrans_kernel<<<dim3(32, 32), tb, 0, stream>>>(wq, wqkvT, D, D);
  wtrans_kernel<<<dim3(32, 32), tb, 0, stream>>>(wk, wqkvT + (size_t)1024 * 1024, D, D);
  wtrans_kernel<<<dim3(32, 32), tb, 0, stream>>>(wv, wqkvT + (size_t)2048 * 1024, D, D);
  wtrans_kernel<<<dim3(32, 32), tb, 0, stream>>>(wo, woT, D, D);
  wtrans_kernel<<<dim3(128, 32), tb, 0, stream>>>(w1, w1T, D, DFF);
  wtrans_kernel<<<dim3(32, 128), tb, 0, stream>>>(w2, w2T, DFF, D);
  hipMemcpyAsync(bqkv, bq, 4096, hipMemcpyDeviceToDevice, stream);
  hipMemcpyAsync(bqkv + 1024, bk, 4096, hipMemcpyDeviceToDevice, stream);
  hipMemcpyAsync(bqkv + 2048, bv, 4096, hipMemcpyDeviceToDevice, stream);

  // h = LN1(x)
  ln_kernel<<<M, 256, 0, stream>>>(x, g1, be1, h);

  // qkv = h @ [wq|wk|wv] + biases; V columns also emitted transposed into vTall
  gemm7<2, true, true, false, false, true><<<24 * 32, 512, 0, stream>>>(
      h, D, 0, wqkvT, D, 0, qkv, 0, bqkv, nullptr, vTall, 3072, D, 1.f, 24, 32);

  for (int b0 = 0; b0 < B; b0 += chunk) {
    int c = (B - b0 < chunk) ? (B - b0) : chunk;
    // scores = q @ k^T * 0.125 (fp32)
    gemm7<4, false, false, false, false, false><<<64 * c, 512, 0, stream>>>(
        qkv + (size_t)b0 * S * 3072, 3072, (size_t)S * 3072,
        qkv + (size_t)b0 * S * 3072 + 1024, 3072, (size_t)S * 3072,
        sc, (size_t)S * S, nullptr, nullptr, nullptr, S, D, 0.125f, 8, 8);
    softmax_kernel<<<c * S, 256, 0, stream>>>(sc);
    // ctx = probs @ vT^T (probs bf16 in-place over fp32 rows, pitch 2S)
    gemm7<2, true, false, false, false, false><<<64 * c, 512, 0, stream>>>(
        (const bf16*)sc, 2 * S, (size_t)S * 2 * S,
        vTall + (size_t)b0 * D * S, S, (size_t)D * S,
        h + (size_t)b0 * S * D, (size_t)S * D, nullptr, nullptr, nullptr, D, S, 1.f, 8, 8);
  }

  // x2 = ctx @ wo + bo + x -> d_out (fp32)
  gemm7<2, false, true, true, false, false><<<8 * 32, 512, 0, stream>>>(
      h, D, 0, woT, D, 0, out, 0, bo, x, nullptr, D, D, 1.f, 8, 32);

  // h = LN2(x2)
  ln_kernel<<<M, 256, 0, stream>>>(out, g2, be2, h);

  // hidden = gelu(h @ w1 + b1)
  gemm7<4, true, true, false, true, false><<<16 * 32, 512, 0, stream>>>(
      h, D, 0, w1T, D, 0, hidden, 0, b1, nullptr, nullptr, DFF, D, 1.f, 16, 32);

  // out = hidden @ w2 + b2 + x2 (in-place residual)
  gemm7<2, false, true, true, false, false><<<8 * 32, 512, 0, stream>>>(
      hidden, DFF, 0, w2T, DFF, 0, out, 0, b2, out, nullptr, D, DFF, 1.f, 8, 32);
}